// Round 1
// baseline (413.227 us; speedup 1.0000x reference)
//
#include <hip/hip_runtime.h>

// SelfAttention: B=4, S=2048, D=1024, fp32 in/out.
// Pipeline (all bf16 MFMA, fp32 accum):
//   cast x,W -> bf16 | Q=x*Wq^T+bq ; K=... ; V=... (V stored transposed [B,D,S])
//   per batch: scores=Q*K^T/32 (fp32) -> softmax -> probs(bf16) -> out=P*Vt^T (fp32)
// ws layout (bytes):
//   [0,16M)   x_bf16  (later aliased: per-batch fp32 scores 2048x2048)
//   [16,32M)  Q bf16   [32,48M) K bf16   [48,64M) Vt bf16 [B][D][S]
//   [64,72M)  probs bf16 (per batch)     [72,78M) Wq/Wk/Wv bf16
// requires ws_size >= 78MB (early-return otherwise -> absmax == max|ref| signature)

typedef __bf16 bf16x8 __attribute__((ext_vector_type(8)));
typedef float f32x4 __attribute__((ext_vector_type(4)));
typedef unsigned short u16;

__device__ __forceinline__ u16 f2b(float f) {
  union { float f; unsigned u; } a; a.f = f;
  unsigned r = a.u + 0x7fffu + ((a.u >> 16) & 1u);  // RNE
  return (u16)(r >> 16);
}

__global__ __launch_bounds__(256) void cast_f2b_kernel(const float* __restrict__ in,
                                                       u16* __restrict__ out, int n4) {
  int i = blockIdx.x * 256 + threadIdx.x;
  if (i < n4) {
    float4 v = reinterpret_cast<const float4*>(in)[i];
    reinterpret_cast<ushort4*>(out)[i] =
        make_ushort4(f2b(v.x), f2b(v.y), f2b(v.z), f2b(v.w));
  }
}

// C = A[M,K] * B[N,K]^T (+bias) ; 128x128 tile, BK=32, 4 waves (2x2), 16x16x32 bf16 MFMA.
// MODE 0: bf16 out [*,1024] + bias        (Q/K projection)
// MODE 1: bf16 out transposed -> Vt[b][n][s], + bias   (V projection)
// MODE 2: fp32 out [*,2048], * scale      (scores)
// MODE 3: fp32 out [*,1024]               (PV)
template <int MODE>
__global__ __launch_bounds__(256) void gemm_nt(const u16* __restrict__ A,
                                               const u16* __restrict__ B,
                                               const float* __restrict__ bias,
                                               void* __restrict__ C, int lda, int ldb,
                                               int K, float scale) {
  constexpr int BM = 128, BN = 128, BK = 32;
  __shared__ __align__(16) u16 As[BM * BK];
  __shared__ __align__(16) u16 Bs[BN * BK];
  const int tid = threadIdx.x;
  const int wave = tid >> 6, lane = tid & 63;
  const int wm = wave >> 1, wn = wave & 1;
  const int tileM = blockIdx.x * BM, tileN = blockIdx.y * BN;

  f32x4 acc[4][4] = {};
  const int srow = lane >> 2;        // row within 16-row staging chunk
  const int scol = (lane & 3) * 8;   // bf16 element offset within row

  for (int k0 = 0; k0 < K; k0 += BK) {
#pragma unroll
    for (int i = 0; i < 2; ++i) {
      const int c = wave + i * 4;  // chunks 0..7, 16 rows each
      const u16* ga = A + (size_t)(tileM + c * 16 + srow) * lda + k0 + scol;
      __builtin_amdgcn_global_load_lds(
          (const __attribute__((address_space(1))) void*)ga,
          (__attribute__((address_space(3))) void*)(As + c * 512), 16, 0, 0);
      const u16* gb = B + (size_t)(tileN + c * 16 + srow) * ldb + k0 + scol;
      __builtin_amdgcn_global_load_lds(
          (const __attribute__((address_space(1))) void*)gb,
          (__attribute__((address_space(3))) void*)(Bs + c * 512), 16, 0, 0);
    }
    __syncthreads();
    const int frow = lane & 15, fk = (lane >> 4) * 8;
    bf16x8 av[4], bv[4];
#pragma unroll
    for (int i = 0; i < 4; ++i) {
      av[i] = *reinterpret_cast<const bf16x8*>(&As[(wm * 64 + i * 16 + frow) * BK + fk]);
      bv[i] = *reinterpret_cast<const bf16x8*>(&Bs[(wn * 64 + i * 16 + frow) * BK + fk]);
    }
#pragma unroll
    for (int i = 0; i < 4; ++i)
#pragma unroll
      for (int j = 0; j < 4; ++j)
        acc[i][j] = __builtin_amdgcn_mfma_f32_16x16x32_bf16(av[i], bv[j], acc[i][j], 0, 0, 0);
    __syncthreads();
  }

  const int crow = (lane >> 4) * 4;  // + reg j
  const int ccol = lane & 15;

  if constexpr (MODE == 0) {
    u16* O = (u16*)C;
#pragma unroll
    for (int i = 0; i < 4; ++i) {
      const int r0 = tileM + wm * 64 + i * 16 + crow;
#pragma unroll
      for (int n = 0; n < 4; ++n) {
        const int cc = tileN + wn * 64 + n * 16 + ccol;
        const float bi = bias[cc];
#pragma unroll
        for (int j = 0; j < 4; ++j)
          O[(size_t)(r0 + j) * 1024 + cc] = f2b(acc[i][n][j] + bi);
      }
    }
  } else if constexpr (MODE == 1) {
    u16* O = (u16*)C;  // Vt base: [B][1024][2048]
#pragma unroll
    for (int i = 0; i < 4; ++i) {
      const int r0 = tileM + wm * 64 + i * 16 + crow;
      const int b = r0 >> 11, s0 = r0 & 2047;
#pragma unroll
      for (int n = 0; n < 4; ++n) {
        const int cc = tileN + wn * 64 + n * 16 + ccol;
        const float bi = bias[cc];
        ushort4 u = make_ushort4(f2b(acc[i][n][0] + bi), f2b(acc[i][n][1] + bi),
                                 f2b(acc[i][n][2] + bi), f2b(acc[i][n][3] + bi));
        *reinterpret_cast<ushort4*>(&O[(size_t)b * 2097152 + (size_t)cc * 2048 + s0]) = u;
      }
    }
  } else if constexpr (MODE == 2) {
    float* O = (float*)C;
#pragma unroll
    for (int i = 0; i < 4; ++i) {
      const int r0 = tileM + wm * 64 + i * 16 + crow;
#pragma unroll
      for (int n = 0; n < 4; ++n) {
        const int cc = tileN + wn * 64 + n * 16 + ccol;
#pragma unroll
        for (int j = 0; j < 4; ++j)
          O[(size_t)(r0 + j) * 2048 + cc] = acc[i][n][j] * scale;
      }
    }
  } else {
    float* O = (float*)C;
#pragma unroll
    for (int i = 0; i < 4; ++i) {
      const int r0 = tileM + wm * 64 + i * 16 + crow;
#pragma unroll
      for (int n = 0; n < 4; ++n) {
        const int cc = tileN + wn * 64 + n * 16 + ccol;
#pragma unroll
        for (int j = 0; j < 4; ++j)
          O[(size_t)(r0 + j) * 1024 + cc] = acc[i][n][j];
      }
    }
  }
}

// Row softmax over 2048 fp32 scores -> 2048 bf16 probs. One block (256 thr) per row.
__global__ __launch_bounds__(256) void softmax_kernel(const float* __restrict__ Sc,
                                                      u16* __restrict__ P) {
  const int row = blockIdx.x;
  const float* sr = Sc + (size_t)row * 2048;
  const int tid = threadIdx.x;
  float4 v0 = reinterpret_cast<const float4*>(sr)[tid * 2];
  float4 v1 = reinterpret_cast<const float4*>(sr)[tid * 2 + 1];
  float m = fmaxf(fmaxf(fmaxf(v0.x, v0.y), fmaxf(v0.z, v0.w)),
                  fmaxf(fmaxf(v1.x, v1.y), fmaxf(v1.z, v1.w)));
#pragma unroll
  for (int o = 32; o; o >>= 1) m = fmaxf(m, __shfl_xor(m, o));
  __shared__ float red[8];
  const int wave = tid >> 6, lane = tid & 63;
  if (lane == 0) red[wave] = m;
  __syncthreads();
  m = fmaxf(fmaxf(red[0], red[1]), fmaxf(red[2], red[3]));
  float e[8];
  e[0] = __expf(v0.x - m); e[1] = __expf(v0.y - m);
  e[2] = __expf(v0.z - m); e[3] = __expf(v0.w - m);
  e[4] = __expf(v1.x - m); e[5] = __expf(v1.y - m);
  e[6] = __expf(v1.z - m); e[7] = __expf(v1.w - m);
  float s = e[0] + e[1] + e[2] + e[3] + e[4] + e[5] + e[6] + e[7];
#pragma unroll
  for (int o = 32; o; o >>= 1) s += __shfl_xor(s, o);
  if (lane == 0) red[4 + wave] = s;
  __syncthreads();
  s = red[4] + red[5] + red[6] + red[7];
  const float inv = 1.0f / s;
  ushort4 ua = make_ushort4(f2b(e[0] * inv), f2b(e[1] * inv), f2b(e[2] * inv), f2b(e[3] * inv));
  ushort4 ub = make_ushort4(f2b(e[4] * inv), f2b(e[5] * inv), f2b(e[6] * inv), f2b(e[7] * inv));
  u16* pr = P + (size_t)row * 2048 + tid * 8;
  *reinterpret_cast<ushort4*>(pr) = ua;
  *reinterpret_cast<ushort4*>(pr + 4) = ub;
}

extern "C" void kernel_launch(void* const* d_in, const int* in_sizes, int n_in,
                              void* d_out, int out_size, void* d_ws, size_t ws_size,
                              hipStream_t stream) {
  if (ws_size < ((size_t)78 << 20)) return;  // diagnosable failure signature
  const float* x = (const float*)d_in[0];
  const float* Wq = (const float*)d_in[1];
  const float* bq = (const float*)d_in[2];
  const float* Wk = (const float*)d_in[3];
  const float* bk = (const float*)d_in[4];
  const float* Wv = (const float*)d_in[5];
  const float* bv = (const float*)d_in[6];
  char* ws = (char*)d_ws;
  u16* xb = (u16*)(ws);
  float* sc = (float*)(ws);  // aliases xb after projections are done
  u16* Qb = (u16*)(ws + ((size_t)16 << 20));
  u16* Kb = (u16*)(ws + ((size_t)32 << 20));
  u16* Vt = (u16*)(ws + ((size_t)48 << 20));
  u16* Pb = (u16*)(ws + ((size_t)64 << 20));
  u16* Wqb = (u16*)(ws + ((size_t)72 << 20));
  u16* Wkb = (u16*)(ws + ((size_t)74 << 20));
  u16* Wvb = (u16*)(ws + ((size_t)76 << 20));
  float* out = (float*)d_out;

  cast_f2b_kernel<<<8192, 256, 0, stream>>>(x, xb, 2097152);
  cast_f2b_kernel<<<1024, 256, 0, stream>>>(Wq, Wqb, 262144);
  cast_f2b_kernel<<<1024, 256, 0, stream>>>(Wk, Wkb, 262144);
  cast_f2b_kernel<<<1024, 256, 0, stream>>>(Wv, Wvb, 262144);

  dim3 gp(64, 8);
  gemm_nt<0><<<gp, 256, 0, stream>>>(xb, Wqb, bq, Qb, 1024, 1024, 1024, 1.0f);
  gemm_nt<0><<<gp, 256, 0, stream>>>(xb, Wkb, bk, Kb, 1024, 1024, 1024, 1.0f);
  gemm_nt<1><<<gp, 256, 0, stream>>>(xb, Wvb, bv, Vt, 1024, 1024, 1024, 1.0f);

  for (int b = 0; b < 4; ++b) {
    const size_t off = (size_t)b * 2097152;  // 2048*1024
    gemm_nt<2><<<dim3(16, 16), 256, 0, stream>>>(Qb + off, Kb + off, nullptr, sc,
                                                 1024, 1024, 1024, 0.03125f);
    softmax_kernel<<<2048, 256, 0, stream>>>(sc, Pb);
    gemm_nt<3><<<dim3(16, 8), 256, 0, stream>>>(Pb, Vt + off, nullptr, out + off,
                                                2048, 2048, 2048, 1.0f);
  }
}

// Round 2
// 219.840 us; speedup vs baseline: 1.8797x; 1.8797x over previous
//
#include <hip/hip_runtime.h>

// SelfAttention: B=4, S=2048, D=1024, fp32 in/out. bf16 MFMA, fp32 accum.
// R1: fully batched launches (proj z=3, scores z=2 x2 into d_out, PV z=4).
// ws layout (MiB):
//   [0,16)  x_bf16 (proj phase)        -> P0,P1 bf16 (after softmax pass 1)
//   [16,32) Q bf16 [4][2048][1024]     -> P2,P3 bf16 (after softmax pass 2)
//   [32,48) K bf16
//   [48,64) Vt bf16 [4][1024][2048]
//   [64,70) Wq/Wk/Wv bf16 (contiguous, 2 MiB each)
// d_out (32 MiB) doubles as fp32 scores scratch for 2 batches per pass.

typedef __bf16 bf16x8 __attribute__((ext_vector_type(8)));
typedef float f32x4 __attribute__((ext_vector_type(4)));
typedef unsigned short u16;

__device__ __forceinline__ u16 f2b(float f) {
  union { float f; unsigned u; } a; a.f = f;
  unsigned r = a.u + 0x7fffu + ((a.u >> 16) & 1u);  // RNE
  return (u16)(r >> 16);
}

__global__ __launch_bounds__(256) void cast_x_kernel(const float* __restrict__ in,
                                                     u16* __restrict__ out, int n4) {
  int i = blockIdx.x * 256 + threadIdx.x;
  if (i < n4) {
    float4 v = reinterpret_cast<const float4*>(in)[i];
    reinterpret_cast<ushort4*>(out)[i] =
        make_ushort4(f2b(v.x), f2b(v.y), f2b(v.z), f2b(v.w));
  }
}

// 3 weights in one dispatch: 1024 blocks per weight (1Mi floats each).
__global__ __launch_bounds__(256) void cast_w_kernel(const float* __restrict__ Wq,
                                                     const float* __restrict__ Wk,
                                                     const float* __restrict__ Wv,
                                                     u16* __restrict__ out) {
  const int b = blockIdx.x;
  const int w = b >> 10;
  const float* src = (w == 0) ? Wq : (w == 1) ? Wk : Wv;
  const int i = (b & 1023) * 256 + threadIdx.x;
  float4 v = reinterpret_cast<const float4*>(src)[i];
  reinterpret_cast<ushort4*>(out + (size_t)w * 1048576)[i] =
      make_ushort4(f2b(v.x), f2b(v.y), f2b(v.z), f2b(v.w));
}

// Shared 128x128 NT GEMM core (BK=32, 4 waves 2x2, 16x16x32 bf16 MFMA,
// global_load_lds width-16 staging). A,B pre-offset to tile origin.
__device__ __forceinline__ void gemm_core(const u16* __restrict__ A,
                                          const u16* __restrict__ B, int lda, int ldb,
                                          int K, u16* As, u16* Bs, f32x4 (*acc)[4]) {
  const int tid = threadIdx.x;
  const int wave = tid >> 6, lane = tid & 63;
  const int wm = wave >> 1, wn = wave & 1;
  const int srow = lane >> 2;       // row within 16-row staging chunk
  const int scol = (lane & 3) * 8;  // bf16 element offset within row
  const int frow = lane & 15, fk = (lane >> 4) * 8;
  for (int k0 = 0; k0 < K; k0 += 32) {
#pragma unroll
    for (int i = 0; i < 2; ++i) {
      const int c = wave + i * 4;  // chunks 0..7, 16 rows each
      const u16* ga = A + (size_t)(c * 16 + srow) * lda + k0 + scol;
      __builtin_amdgcn_global_load_lds(
          (const __attribute__((address_space(1))) void*)ga,
          (__attribute__((address_space(3))) void*)(As + c * 512), 16, 0, 0);
      const u16* gb = B + (size_t)(c * 16 + srow) * ldb + k0 + scol;
      __builtin_amdgcn_global_load_lds(
          (const __attribute__((address_space(1))) void*)gb,
          (__attribute__((address_space(3))) void*)(Bs + c * 512), 16, 0, 0);
    }
    __syncthreads();
    bf16x8 av[4], bv[4];
#pragma unroll
    for (int i = 0; i < 4; ++i) {
      av[i] = *reinterpret_cast<const bf16x8*>(&As[(wm * 64 + i * 16 + frow) * 32 + fk]);
      bv[i] = *reinterpret_cast<const bf16x8*>(&Bs[(wn * 64 + i * 16 + frow) * 32 + fk]);
    }
#pragma unroll
    for (int i = 0; i < 4; ++i)
#pragma unroll
      for (int j = 0; j < 4; ++j)
        acc[i][j] = __builtin_amdgcn_mfma_f32_16x16x32_bf16(av[i], bv[j], acc[i][j], 0, 0, 0);
    __syncthreads();
  }
}

// Projections: z=0 -> Q, z=1 -> K (row-major bf16 + bias), z=2 -> Vt (transposed + bias).
__global__ __launch_bounds__(256) void proj_kernel(const u16* __restrict__ xb,
                                                   const u16* __restrict__ Wb,
                                                   const float* __restrict__ bq,
                                                   const float* __restrict__ bk,
                                                   const float* __restrict__ bvv,
                                                   u16* __restrict__ QK,
                                                   u16* __restrict__ Vt) {
  __shared__ __align__(16) u16 As[128 * 32];
  __shared__ __align__(16) u16 Bs[128 * 32];
  const int z = blockIdx.z;
  const int tileM = blockIdx.x * 128, tileN = blockIdx.y * 128;
  f32x4 acc[4][4] = {};
  gemm_core(xb + (size_t)tileM * 1024, Wb + (size_t)z * 1048576 + (size_t)tileN * 1024,
            1024, 1024, 1024, As, Bs, acc);
  const int lane = threadIdx.x & 63, wave = threadIdx.x >> 6;
  const int wm = wave >> 1, wn = wave & 1;
  const int crow = (lane >> 4) * 4, ccol = lane & 15;
  const float* bias = (z == 0) ? bq : (z == 1) ? bk : bvv;
  if (z < 2) {
    u16* O = QK + (size_t)z * 8388608;
#pragma unroll
    for (int i = 0; i < 4; ++i) {
      const int r0 = tileM + wm * 64 + i * 16 + crow;
#pragma unroll
      for (int n = 0; n < 4; ++n) {
        const int cc = tileN + wn * 64 + n * 16 + ccol;
        const float bi = bias[cc];
#pragma unroll
        for (int j = 0; j < 4; ++j)
          O[(size_t)(r0 + j) * 1024 + cc] = f2b(acc[i][n][j] + bi);
      }
    }
  } else {
#pragma unroll
    for (int i = 0; i < 4; ++i) {
      const int r0 = tileM + wm * 64 + i * 16 + crow;
      const int b = r0 >> 11, s0 = r0 & 2047;
#pragma unroll
      for (int n = 0; n < 4; ++n) {
        const int cc = tileN + wn * 64 + n * 16 + ccol;
        const float bi = bias[cc];
        ushort4 u = make_ushort4(f2b(acc[i][n][0] + bi), f2b(acc[i][n][1] + bi),
                                 f2b(acc[i][n][2] + bi), f2b(acc[i][n][3] + bi));
        *reinterpret_cast<ushort4*>(&Vt[(size_t)b * 2097152 + (size_t)cc * 2048 + s0]) = u;
      }
    }
  }
}

// Scores: z = batch-within-pass (2 per pass). Sc = Q[b] * K[b]^T / 32, fp32 out.
__global__ __launch_bounds__(256) void sc_kernel(const u16* __restrict__ Qb,
                                                 const u16* __restrict__ Kb,
                                                 float* __restrict__ Sc, int b0) {
  __shared__ __align__(16) u16 As[128 * 32];
  __shared__ __align__(16) u16 Bs[128 * 32];
  const int z = blockIdx.z, batch = b0 + z;
  const int tileM = blockIdx.x * 128, tileN = blockIdx.y * 128;
  f32x4 acc[4][4] = {};
  gemm_core(Qb + (size_t)batch * 2097152 + (size_t)tileM * 1024,
            Kb + (size_t)batch * 2097152 + (size_t)tileN * 1024, 1024, 1024, 1024, As, Bs,
            acc);
  float* O = Sc + (size_t)z * 4194304;
  const int lane = threadIdx.x & 63, wave = threadIdx.x >> 6;
  const int wm = wave >> 1, wn = wave & 1;
  const int crow = (lane >> 4) * 4, ccol = lane & 15;
#pragma unroll
  for (int i = 0; i < 4; ++i) {
    const int r0 = tileM + wm * 64 + i * 16 + crow;
#pragma unroll
    for (int n = 0; n < 4; ++n) {
      const int cc = tileN + wn * 64 + n * 16 + ccol;
#pragma unroll
      for (int j = 0; j < 4; ++j)
        O[(size_t)(r0 + j) * 2048 + cc] = acc[i][n][j] * 0.03125f;
    }
  }
}

// PV: z = batch 0..3. out[b] = P[b] * Vt[b]^T, fp32 out.
__global__ __launch_bounds__(256) void pv_kernel(const u16* __restrict__ P,
                                                 const u16* __restrict__ Vt,
                                                 float* __restrict__ out) {
  __shared__ __align__(16) u16 As[128 * 32];
  __shared__ __align__(16) u16 Bs[128 * 32];
  const int z = blockIdx.z;
  const int tileM = blockIdx.x * 128, tileN = blockIdx.y * 128;
  f32x4 acc[4][4] = {};
  gemm_core(P + (size_t)z * 4194304 + (size_t)tileM * 2048,
            Vt + (size_t)z * 2097152 + (size_t)tileN * 2048, 2048, 2048, 2048, As, Bs,
            acc);
  float* O = out + (size_t)z * 2097152;
  const int lane = threadIdx.x & 63, wave = threadIdx.x >> 6;
  const int wm = wave >> 1, wn = wave & 1;
  const int crow = (lane >> 4) * 4, ccol = lane & 15;
#pragma unroll
  for (int i = 0; i < 4; ++i) {
    const int r0 = tileM + wm * 64 + i * 16 + crow;
#pragma unroll
    for (int n = 0; n < 4; ++n) {
      const int cc = tileN + wn * 64 + n * 16 + ccol;
#pragma unroll
      for (int j = 0; j < 4; ++j)
        O[(size_t)(r0 + j) * 1024 + cc] = acc[i][n][j];
    }
  }
}

// Row softmax over 2048 fp32 scores -> 2048 bf16 probs. One block per row, 4096 rows/pass.
__global__ __launch_bounds__(256) void softmax_kernel(const float* __restrict__ Sc,
                                                      u16* __restrict__ P) {
  const int row = blockIdx.x;
  const float* sr = Sc + (size_t)row * 2048;
  const int tid = threadIdx.x;
  float4 v0 = reinterpret_cast<const float4*>(sr)[tid * 2];
  float4 v1 = reinterpret_cast<const float4*>(sr)[tid * 2 + 1];
  float m = fmaxf(fmaxf(fmaxf(v0.x, v0.y), fmaxf(v0.z, v0.w)),
                  fmaxf(fmaxf(v1.x, v1.y), fmaxf(v1.z, v1.w)));
#pragma unroll
  for (int o = 32; o; o >>= 1) m = fmaxf(m, __shfl_xor(m, o));
  __shared__ float red[8];
  const int wave = tid >> 6, lane = tid & 63;
  if (lane == 0) red[wave] = m;
  __syncthreads();
  m = fmaxf(fmaxf(red[0], red[1]), fmaxf(red[2], red[3]));
  float e[8];
  e[0] = __expf(v0.x - m); e[1] = __expf(v0.y - m);
  e[2] = __expf(v0.z - m); e[3] = __expf(v0.w - m);
  e[4] = __expf(v1.x - m); e[5] = __expf(v1.y - m);
  e[6] = __expf(v1.z - m); e[7] = __expf(v1.w - m);
  float s = e[0] + e[1] + e[2] + e[3] + e[4] + e[5] + e[6] + e[7];
#pragma unroll
  for (int o = 32; o; o >>= 1) s += __shfl_xor(s, o);
  if (lane == 0) red[4 + wave] = s;
  __syncthreads();
  s = red[4] + red[5] + red[6] + red[7];
  const float inv = 1.0f / s;
  ushort4 ua = make_ushort4(f2b(e[0] * inv), f2b(e[1] * inv), f2b(e[2] * inv), f2b(e[3] * inv));
  ushort4 ub = make_ushort4(f2b(e[4] * inv), f2b(e[5] * inv), f2b(e[6] * inv), f2b(e[7] * inv));
  u16* pr = P + (size_t)row * 2048 + tid * 8;
  *reinterpret_cast<ushort4*>(pr) = ua;
  *reinterpret_cast<ushort4*>(pr + 4) = ub;
}

extern "C" void kernel_launch(void* const* d_in, const int* in_sizes, int n_in,
                              void* d_out, int out_size, void* d_ws, size_t ws_size,
                              hipStream_t stream) {
  if (ws_size < ((size_t)72 << 20)) return;  // need 70 MiB; diagnosable signature
  const float* x = (const float*)d_in[0];
  const float* Wq = (const float*)d_in[1];
  const float* bq = (const float*)d_in[2];
  const float* Wk = (const float*)d_in[3];
  const float* bk = (const float*)d_in[4];
  const float* Wv = (const float*)d_in[5];
  const float* bv = (const float*)d_in[6];
  char* ws = (char*)d_ws;
  u16* xb = (u16*)(ws);                       // [0,16M), later P0..P3 at [0,32M)
  u16* Pb = (u16*)(ws);
  u16* Qb = (u16*)(ws + ((size_t)16 << 20));  // [16,32M)
  u16* Kb = (u16*)(ws + ((size_t)32 << 20));  // [32,48M)
  u16* Vt = (u16*)(ws + ((size_t)48 << 20));  // [48,64M) [4][1024][2048]
  u16* Wb = (u16*)(ws + ((size_t)64 << 20));  // [64,70M) Wq|Wk|Wv bf16
  float* out = (float*)d_out;
  float* scD = (float*)d_out;  // 32 MiB scores scratch (2 batches per pass)

  cast_x_kernel<<<8192, 256, 0, stream>>>(x, xb, 2097152);
  cast_w_kernel<<<3072, 256, 0, stream>>>(Wq, Wk, Wv, Wb);

  proj_kernel<<<dim3(64, 8, 3), 256, 0, stream>>>(xb, Wb, bq, bk, bv, Qb, Vt);

  // pass 1: batches 0,1 -> scores in d_out -> P0,P1 over dead xb region
  sc_kernel<<<dim3(16, 16, 2), 256, 0, stream>>>(Qb, Kb, scD, 0);
  softmax_kernel<<<4096, 256, 0, stream>>>(scD, Pb);
  // pass 2: batches 2,3 -> P2,P3 over dead Q region (Q unused after this sc)
  sc_kernel<<<dim3(16, 16, 2), 256, 0, stream>>>(Qb, Kb, scD, 2);
  softmax_kernel<<<4096, 256, 0, stream>>>(scD, Pb + 8388608);

  pv_kernel<<<dim3(16, 8, 4), 256, 0, stream>>>(Pb, Vt, out);
}

// Round 3
// 212.026 us; speedup vs baseline: 1.9489x; 1.0369x over previous
//
#include <hip/hip_runtime.h>

// SelfAttention: B=4, S=2048, D=1024, fp32 in/out. bf16 MFMA, fp32 accum.
// R2: QKV projection moved to a 256x256 8-phase counted-vmcnt kernel (T2+T3+T4+T5).
// sc / softmax / PV unchanged from R1 (validated).
// ws layout (MiB):
//   [0,16)  x_bf16 (proj phase)        -> P0,P1 bf16 (after softmax pass 1)
//   [16,32) Q bf16 [4][2048][1024]     -> P2,P3 bf16 (after softmax pass 2)
//   [32,48) K bf16
//   [48,64) Vt bf16 [4][1024][2048]
//   [64,70) Wq|Wk|Wv bf16 (contiguous [3072][1024])
// d_out (32 MiB) doubles as fp32 scores scratch (2 batches per pass).

typedef __bf16 bf16x8 __attribute__((ext_vector_type(8)));
typedef float f32x4 __attribute__((ext_vector_type(4)));
typedef unsigned short u16;

__device__ __forceinline__ u16 f2b(float f) {
  union { float f; unsigned u; } a; a.f = f;
  unsigned r = a.u + 0x7fffu + ((a.u >> 16) & 1u);  // RNE
  return (u16)(r >> 16);
}

__global__ __launch_bounds__(256) void cast_x_kernel(const float* __restrict__ in,
                                                     u16* __restrict__ out, int n4) {
  int i = blockIdx.x * 256 + threadIdx.x;
  if (i < n4) {
    float4 v = reinterpret_cast<const float4*>(in)[i];
    reinterpret_cast<ushort4*>(out)[i] =
        make_ushort4(f2b(v.x), f2b(v.y), f2b(v.z), f2b(v.w));
  }
}

__global__ __launch_bounds__(256) void cast_w_kernel(const float* __restrict__ Wq,
                                                     const float* __restrict__ Wk,
                                                     const float* __restrict__ Wv,
                                                     u16* __restrict__ out) {
  const int b = blockIdx.x;
  const int w = b >> 10;
  const float* src = (w == 0) ? Wq : (w == 1) ? Wk : Wv;
  const int i = (b & 1023) * 256 + threadIdx.x;
  float4 v = reinterpret_cast<const float4*>(src)[i];
  reinterpret_cast<ushort4*>(out + (size_t)w * 1048576)[i] =
      make_ushort4(f2b(v.x), f2b(v.y), f2b(v.z), f2b(v.w));
}

// ---------------- 8-phase 256x256 NT GEMM: QKV projection ----------------
// A = xb [8192][1024], B = Wb [3072][1024] (bf16, NT). w = by>>2 selects output:
// 0/1 -> Q/K row-major bf16 + bias; 2 -> Vt [b][1024][2048] transposed + bias.
// LDS per buffer: A-tile 32KB ([ks-half 16KB][16 R-subtiles x 1024B]), B same.
// st_16x32 swizzle within each 1024B subtile: byte ^= ((row>>3)&1)<<5.
__global__ __launch_bounds__(512, 2) void proj8_kernel(
    const u16* __restrict__ A, const u16* __restrict__ Bm,
    const float* __restrict__ bq, const float* __restrict__ bk,
    const float* __restrict__ bvv, u16* __restrict__ QK, u16* __restrict__ Vt) {
  extern __shared__ char smem[];  // 131072 bytes
  constexpr int NT = 16;          // K=1024 / BK=64
  const int tid = threadIdx.x;
  const int wave = tid >> 6, lane = tid & 63;
  const int wr = wave >> 2, wc = wave & 3;  // 2 x 4 wave grid, 128x64 per wave
  const int tileM = blockIdx.x * 256;
  const int tileN = blockIdx.y * 256;

  // ds_read per-lane swizzled offset within a subtile (frag: row=lane&15, k8=(lane>>4)*8)
  const int fr = lane & 15, fg = lane >> 4;
  const int rd_inner = (fr * 64 + fg * 16) ^ (((fr >> 3) & 1) << 5);

  // staging: physical LDS byte P = i*8192 + wave*1024 + lane*16 holds logical
  // inner byte li = (lane*16) ^ bit5-flip-by-bit9 -> (row sr, col-byte sc2)
  const int li = (lane * 16) ^ ((lane >> 5) << 5);
  const int sr = li >> 6, sc2 = li & 63;
  const int rowA0 = wave * 16 + sr;        // i=0: R-subtile = wave
  const int rowA1 = 128 + wave * 16 + sr;  // i=1: R-subtile = 8+wave

  const char* Ab = (const char*)A + (size_t)tileM * 2048;
  const char* Bb = (const char*)Bm + (size_t)tileN * 2048;

  // stage half p (0:A-ks0, 1:B-ks0, 2:A-ks1, 3:B-ks1) of tile kt -> buf[kt&1]
  auto STAGE = [&](int kt, int p) {
    const int isB = p & 1, s = p >> 1;
    char* ldsHalf = smem + (kt & 1) * 65536 + isB * 32768 + s * 16384;
    const char* gb = isB ? Bb : Ab;
    const int colOff = kt * 128 + s * 64;  // bytes within row
    const char* g0 = gb + (size_t)rowA0 * 2048 + colOff + sc2;
    const char* g1 = gb + (size_t)rowA1 * 2048 + colOff + sc2;
    __builtin_amdgcn_global_load_lds(
        (const __attribute__((address_space(1))) void*)g0,
        (__attribute__((address_space(3))) void*)(ldsHalf + wave * 1024), 16, 0, 0);
    __builtin_amdgcn_global_load_lds(
        (const __attribute__((address_space(1))) void*)g1,
        (__attribute__((address_space(3))) void*)(ldsHalf + 8192 + wave * 1024), 16, 0, 0);
  };

  // prologue: 4 halves of tile 0; land first 2, keep 2 in flight (steady entry state)
#pragma unroll
  for (int p = 0; p < 4; ++p) STAGE(0, p);
  asm volatile("s_waitcnt vmcnt(4)" ::: "memory");
  __builtin_amdgcn_s_barrier();
  __builtin_amdgcn_sched_barrier(0);

  f32x4 acc[8][4] = {};
  bf16x8 bfr[4];

  for (int kt = 0; kt < NT; ++kt) {
    const char* bufA = smem + (kt & 1) * 65536;
    const char* bufB = bufA + 32768;
    const bool notlast = (kt + 1 < NT);
#pragma unroll
    for (int p = 0; p < 4; ++p) {
      const int s = p >> 1, j = p & 1;
      bf16x8 afr[4];
      if (j == 0) {
#pragma unroll
        for (int n = 0; n < 4; ++n)
          bfr[n] = *reinterpret_cast<const bf16x8*>(bufB + s * 16384 +
                                                    (wc * 4 + n) * 1024 + rd_inner);
      }
#pragma unroll
      for (int m = 0; m < 4; ++m)
        afr[m] = *reinterpret_cast<const bf16x8*>(bufA + s * 16384 +
                                                  (wr * 8 + j * 4 + m) * 1024 + rd_inner);
      if (notlast) STAGE(kt + 1, p);
      __builtin_amdgcn_s_barrier();
      __builtin_amdgcn_sched_barrier(0);
      __builtin_amdgcn_s_setprio(1);
#pragma unroll
      for (int m = 0; m < 4; ++m)
#pragma unroll
        for (int n = 0; n < 4; ++n)
          acc[j * 4 + m][n] = __builtin_amdgcn_mfma_f32_16x16x32_bf16(
              afr[m], bfr[n], acc[j * 4 + m][n], 0, 0, 0);
      __builtin_amdgcn_s_setprio(0);
      if (p == 1 || p == 3) {
        if (notlast) asm volatile("s_waitcnt vmcnt(4)" ::: "memory");
        else asm volatile("s_waitcnt vmcnt(0)" ::: "memory");
      }
      __builtin_amdgcn_s_barrier();
      __builtin_amdgcn_sched_barrier(0);
    }
  }

  // epilogue: C row = tileM + wr*128 + mi*16 + fg*4 + jj ; col = tileN + wc*64 + n*16 + fr
  const int w = blockIdx.y >> 2;  // weight id (256-col tiles never straddle weights)
  const float* bias = (w == 0) ? bq : (w == 1) ? bk : bvv;
  if (w < 2) {
    u16* O = QK + (size_t)w * 8388608;
#pragma unroll
    for (int mi = 0; mi < 8; ++mi) {
      const int r0 = tileM + wr * 128 + mi * 16 + fg * 4;
#pragma unroll
      for (int n = 0; n < 4; ++n) {
        const int cw = (tileN + wc * 64 + n * 16 + fr) & 1023;
        const float bi = bias[cw];
#pragma unroll
        for (int jj = 0; jj < 4; ++jj)
          O[(size_t)(r0 + jj) * 1024 + cw] = f2b(acc[mi][n][jj] + bi);
      }
    }
  } else {
#pragma unroll
    for (int mi = 0; mi < 8; ++mi) {
      const int r0 = tileM + wr * 128 + mi * 16 + fg * 4;
      const int b = r0 >> 11, s0 = r0 & 2047;
#pragma unroll
      for (int n = 0; n < 4; ++n) {
        const int cw = (tileN + wc * 64 + n * 16 + fr) & 1023;
        const float bi = bias[cw];
        ushort4 u = make_ushort4(f2b(acc[mi][n][0] + bi), f2b(acc[mi][n][1] + bi),
                                 f2b(acc[mi][n][2] + bi), f2b(acc[mi][n][3] + bi));
        *reinterpret_cast<ushort4*>(&Vt[(size_t)b * 2097152 + (size_t)cw * 2048 + s0]) = u;
      }
    }
  }
}

// ---------------- validated 128x128 2-phase core (sc / PV) ----------------
__device__ __forceinline__ void gemm_core(const u16* __restrict__ A,
                                          const u16* __restrict__ B, int lda, int ldb,
                                          int K, u16* As, u16* Bs, f32x4 (*acc)[4]) {
  const int tid = threadIdx.x;
  const int wave = tid >> 6, lane = tid & 63;
  const int wm = wave >> 1, wn = wave & 1;
  const int srow = lane >> 2;
  const int scol = (lane & 3) * 8;
  const int frow = lane & 15, fk = (lane >> 4) * 8;
  for (int k0 = 0; k0 < K; k0 += 32) {
#pragma unroll
    for (int i = 0; i < 2; ++i) {
      const int c = wave + i * 4;
      const u16* ga = A + (size_t)(c * 16 + srow) * lda + k0 + scol;
      __builtin_amdgcn_global_load_lds(
          (const __attribute__((address_space(1))) void*)ga,
          (__attribute__((address_space(3))) void*)(As + c * 512), 16, 0, 0);
      const u16* gb = B + (size_t)(c * 16 + srow) * ldb + k0 + scol;
      __builtin_amdgcn_global_load_lds(
          (const __attribute__((address_space(1))) void*)gb,
          (__attribute__((address_space(3))) void*)(Bs + c * 512), 16, 0, 0);
    }
    __syncthreads();
    bf16x8 av[4], bv[4];
#pragma unroll
    for (int i = 0; i < 4; ++i) {
      av[i] = *reinterpret_cast<const bf16x8*>(&As[(wm * 64 + i * 16 + frow) * 32 + fk]);
      bv[i] = *reinterpret_cast<const bf16x8*>(&Bs[(wn * 64 + i * 16 + frow) * 32 + fk]);
    }
#pragma unroll
    for (int i = 0; i < 4; ++i)
#pragma unroll
      for (int j = 0; j < 4; ++j)
        acc[i][j] = __builtin_amdgcn_mfma_f32_16x16x32_bf16(av[i], bv[j], acc[i][j], 0, 0, 0);
    __syncthreads();
  }
}

__global__ __launch_bounds__(256) void sc_kernel(const u16* __restrict__ Qb,
                                                 const u16* __restrict__ Kb,
                                                 float* __restrict__ Sc, int b0) {
  __shared__ __align__(16) u16 As[128 * 32];
  __shared__ __align__(16) u16 Bs[128 * 32];
  const int z = blockIdx.z, batch = b0 + z;
  const int tileM = blockIdx.x * 128, tileN = blockIdx.y * 128;
  f32x4 acc[4][4] = {};
  gemm_core(Qb + (size_t)batch * 2097152 + (size_t)tileM * 1024,
            Kb + (size_t)batch * 2097152 + (size_t)tileN * 1024, 1024, 1024, 1024, As, Bs,
            acc);
  float* O = Sc + (size_t)z * 4194304;
  const int lane = threadIdx.x & 63, wave = threadIdx.x >> 6;
  const int wm = wave >> 1, wn = wave & 1;
  const int crow = (lane >> 4) * 4, ccol = lane & 15;
#pragma unroll
  for (int i = 0; i < 4; ++i) {
    const int r0 = tileM + wm * 64 + i * 16 + crow;
#pragma unroll
    for (int n = 0; n < 4; ++n) {
      const int cc = tileN + wn * 64 + n * 16 + ccol;
#pragma unroll
      for (int j = 0; j < 4; ++j)
        O[(size_t)(r0 + j) * 2048 + cc] = acc[i][n][j] * 0.03125f;
    }
  }
}

__global__ __launch_bounds__(256) void pv_kernel(const u16* __restrict__ P,
                                                 const u16* __restrict__ Vt,
                                                 float* __restrict__ out) {
  __shared__ __align__(16) u16 As[128 * 32];
  __shared__ __align__(16) u16 Bs[128 * 32];
  const int z = blockIdx.z;
  const int tileM = blockIdx.x * 128, tileN = blockIdx.y * 128;
  f32x4 acc[4][4] = {};
  gemm_core(P + (size_t)z * 4194304 + (size_t)tileM * 2048,
            Vt + (size_t)z * 2097152 + (size_t)tileN * 2048, 2048, 2048, 2048, As, Bs,
            acc);
  float* O = out + (size_t)z * 2097152;
  const int lane = threadIdx.x & 63, wave = threadIdx.x >> 6;
  const int wm = wave >> 1, wn = wave & 1;
  const int crow = (lane >> 4) * 4, ccol = lane & 15;
#pragma unroll
  for (int i = 0; i < 4; ++i) {
    const int r0 = tileM + wm * 64 + i * 16 + crow;
#pragma unroll
    for (int n = 0; n < 4; ++n) {
      const int cc = tileN + wn * 64 + n * 16 + ccol;
#pragma unroll
      for (int j = 0; j < 4; ++j)
        O[(size_t)(r0 + j) * 1024 + cc] = acc[i][n][j];
    }
  }
}

__global__ __launch_bounds__(256) void softmax_kernel(const float* __restrict__ Sc,
                                                      u16* __restrict__ P) {
  const int row = blockIdx.x;
  const float* sr = Sc + (size_t)row * 2048;
  const int tid = threadIdx.x;
  float4 v0 = reinterpret_cast<const float4*>(sr)[tid * 2];
  float4 v1 = reinterpret_cast<const float4*>(sr)[tid * 2 + 1];
  float m = fmaxf(fmaxf(fmaxf(v0.x, v0.y), fmaxf(v0.z, v0.w)),
                  fmaxf(fmaxf(v1.x, v1.y), fmaxf(v1.z, v1.w)));
#pragma unroll
  for (int o = 32; o; o >>= 1) m = fmaxf(m, __shfl_xor(m, o));
  __shared__ float red[8];
  const int wave = tid >> 6, lane = tid & 63;
  if (lane == 0) red[wave] = m;
  __syncthreads();
  m = fmaxf(fmaxf(red[0], red[1]), fmaxf(red[2], red[3]));
  float e[8];
  e[0] = __expf(v0.x - m); e[1] = __expf(v0.y - m);
  e[2] = __expf(v0.z - m); e[3] = __expf(v0.w - m);
  e[4] = __expf(v1.x - m); e[5] = __expf(v1.y - m);
  e[6] = __expf(v1.z - m); e[7] = __expf(v1.w - m);
  float s = e[0] + e[1] + e[2] + e[3] + e[4] + e[5] + e[6] + e[7];
#pragma unroll
  for (int o = 32; o; o >>= 1) s += __shfl_xor(s, o);
  if (lane == 0) red[4 + wave] = s;
  __syncthreads();
  s = red[4] + red[5] + red[6] + red[7];
  const float inv = 1.0f / s;
  ushort4 ua = make_ushort4(f2b(e[0] * inv), f2b(e[1] * inv), f2b(e[2] * inv), f2b(e[3] * inv));
  ushort4 ub = make_ushort4(f2b(e[4] * inv), f2b(e[5] * inv), f2b(e[6] * inv), f2b(e[7] * inv));
  u16* pr = P + (size_t)row * 2048 + tid * 8;
  *reinterpret_cast<ushort4*>(pr) = ua;
  *reinterpret_cast<ushort4*>(pr + 4) = ub;
}

extern "C" void kernel_launch(void* const* d_in, const int* in_sizes, int n_in,
                              void* d_out, int out_size, void* d_ws, size_t ws_size,
                              hipStream_t stream) {
  if (ws_size < ((size_t)72 << 20)) return;
  const float* x = (const float*)d_in[0];
  const float* Wq = (const float*)d_in[1];
  const float* bq = (const float*)d_in[2];
  const float* Wk = (const float*)d_in[3];
  const float* bk = (const float*)d_in[4];
  const float* Wv = (const float*)d_in[5];
  const float* bv = (const float*)d_in[6];
  char* ws = (char*)d_ws;
  u16* xb = (u16*)(ws);
  u16* Pb = (u16*)(ws);
  u16* Qb = (u16*)(ws + ((size_t)16 << 20));
  u16* Kb = (u16*)(ws + ((size_t)32 << 20));
  u16* Vt = (u16*)(ws + ((size_t)48 << 20));
  u16* Wb = (u16*)(ws + ((size_t)64 << 20));
  float* out = (float*)d_out;
  float* scD = (float*)d_out;

  (void)hipFuncSetAttribute((const void*)proj8_kernel,
                            hipFuncAttributeMaxDynamicSharedMemorySize, 131072);

  cast_x_kernel<<<8192, 256, 0, stream>>>(x, xb, 2097152);
  cast_w_kernel<<<3072, 256, 0, stream>>>(Wq, Wk, Wv, Wb);

  proj8_kernel<<<dim3(32, 12), 512, 131072, stream>>>(xb, Wb, bq, bk, bv, Qb, Vt);

  sc_kernel<<<dim3(16, 16, 2), 256, 0, stream>>>(Qb, Kb, scD, 0);
  softmax_kernel<<<4096, 256, 0, stream>>>(scD, Pb);
  sc_kernel<<<dim3(16, 16, 2), 256, 0, stream>>>(Qb, Kb, scD, 2);
  softmax_kernel<<<4096, 256, 0, stream>>>(scD, Pb + 8388608);

  pv_kernel<<<dim3(16, 8, 4), 256, 0, stream>>>(Pb, Vt, out);
}

// Round 4
// 161.941 us; speedup vs baseline: 2.5517x; 1.3093x over previous
//
#include <hip/hip_runtime.h>

// SelfAttention: B=4, S=2048, D=1024, fp32 in/out. bf16 MFMA, fp32 accum.
// R3: softmax-free attention. sc = exp(QK^T/32) -> bf16 P~ (unnormalized) + row-sum
// partials; tiny rsum kernel -> 1/rowsum; pv multiplies at epilogue.
// sc: 256x256 8-phase, grid 8x8x4 = 256 blocks (exact fill).
// pv: 128x256 8-phase (GEOM 1), grid 16x4x4 = 256 blocks (exact fill).
// proj: unchanged validated R2 kernel (384 blocks, known 73.5us).
// ws layout (MiB):
//   [0,16)   x_bf16 (proj) -> P~ bf16 [4][2048][2048] (sc output)
//   [16,32)  Q bf16 [4][2048][1024]
//   [32,48)  K bf16
//   [48,64)  Vt bf16 [4][1024][2048]
//   [64,70)  Wq|Wk|Wv bf16
//   [70,70.25) rowpart fp32 [8 ntiles][4][2048]   [70.25,+32K) rowinv fp32 [4][2048]

typedef __bf16 bf16x8 __attribute__((ext_vector_type(8)));
typedef float f32x4 __attribute__((ext_vector_type(4)));
typedef unsigned short u16;

__device__ __forceinline__ u16 f2b(float f) {
  union { float f; unsigned u; } a; a.f = f;
  unsigned r = a.u + 0x7fffu + ((a.u >> 16) & 1u);  // RNE
  return (u16)(r >> 16);
}

__global__ __launch_bounds__(256) void cast_x_kernel(const float* __restrict__ in,
                                                     u16* __restrict__ out, int n4) {
  int i = blockIdx.x * 256 + threadIdx.x;
  if (i < n4) {
    float4 v = reinterpret_cast<const float4*>(in)[i];
    reinterpret_cast<ushort4*>(out)[i] =
        make_ushort4(f2b(v.x), f2b(v.y), f2b(v.z), f2b(v.w));
  }
}

__global__ __launch_bounds__(256) void cast_w_kernel(const float* __restrict__ Wq,
                                                     const float* __restrict__ Wk,
                                                     const float* __restrict__ Wv,
                                                     u16* __restrict__ out) {
  const int b = blockIdx.x;
  const int w = b >> 10;
  const float* src = (w == 0) ? Wq : (w == 1) ? Wk : Wv;
  const int i = (b & 1023) * 256 + threadIdx.x;
  float4 v = reinterpret_cast<const float4*>(src)[i];
  reinterpret_cast<ushort4*>(out + (size_t)w * 1048576)[i] =
      make_ushort4(f2b(v.x), f2b(v.y), f2b(v.z), f2b(v.w));
}

// ---------------- shared 8-phase core ----------------
// GEOM 0: BM=256,BN=256 (acc = f32x4[32]); GEOM 1: BM=128,BN=256 (acc = f32x4[16]).
// 8 waves: wr=wave>>2 (M), wc=wave&3 (N). BK=64, NT K-tiles. lda/ldb in BYTES.
template <int GEOM, int NT>
__device__ __forceinline__ void core8(const char* __restrict__ Ab,
                                      const char* __restrict__ Bb, int lda, int ldb,
                                      char* smem, f32x4* acc) {
  constexpr int LDSBUF = GEOM ? 49152 : 65536;
  constexpr int BOFF = GEOM ? 16384 : 32768;
  constexpr int AHALF = GEOM ? 8192 : 16384;
  const int tid = threadIdx.x;
  const int wave = tid >> 6, lane = tid & 63;
  const int wr = wave >> 2, wc = wave & 3;
  const int fr = lane & 15, fg = lane >> 4;
  const int rd = (fr * 64 + fg * 16) ^ (((fr >> 3) & 1) << 5);
  const int li = (lane * 16) ^ ((lane >> 5) << 5);
  const int sr = li >> 6, sc2 = li & 63;

  auto STAGE = [&](int kt, int p) {
    const int isB = p & 1, s = p >> 1;
    char* lds = smem + (kt & 1) * LDSBUF + (isB ? BOFF + s * 16384 : s * AHALF);
    const char* gb = isB ? Bb : Ab;
    const int ldx = isB ? ldb : lda;
    const int colOff = kt * 128 + s * 64 + sc2;
    __builtin_amdgcn_global_load_lds(
        (const __attribute__((address_space(1))) void*)(gb + (size_t)(wave * 16 + sr) * ldx + colOff),
        (__attribute__((address_space(3))) void*)(lds + wave * 1024), 16, 0, 0);
    if (isB || GEOM == 0)
      __builtin_amdgcn_global_load_lds(
          (const __attribute__((address_space(1))) void*)(gb + (size_t)((8 + wave) * 16 + sr) * ldx + colOff),
          (__attribute__((address_space(3))) void*)(lds + 8192 + wave * 1024), 16, 0, 0);
  };

#pragma unroll
  for (int p = 0; p < 4; ++p) STAGE(0, p);
  if constexpr (GEOM == 0) asm volatile("s_waitcnt vmcnt(4)" ::: "memory");
  else asm volatile("s_waitcnt vmcnt(3)" ::: "memory");
  __builtin_amdgcn_s_barrier();
  __builtin_amdgcn_sched_barrier(0);

  bf16x8 keep[4];  // GEOM0: B frags held across j; GEOM1: A frags held across j
  for (int kt = 0; kt < NT; ++kt) {
    const char* bufA = smem + (kt & 1) * LDSBUF;
    const char* bufB = bufA + BOFF;
    const bool notlast = (kt + 1 < NT);
#pragma unroll
    for (int p = 0; p < 4; ++p) {
      const int s = p >> 1, j = p & 1;
      if constexpr (GEOM == 0) {
        bf16x8 afr[4];
        if (j == 0)
#pragma unroll
          for (int n = 0; n < 4; ++n)
            keep[n] = *reinterpret_cast<const bf16x8*>(bufB + s * 16384 + (wc * 4 + n) * 1024 + rd);
#pragma unroll
        for (int m = 0; m < 4; ++m)
          afr[m] = *reinterpret_cast<const bf16x8*>(bufA + s * 16384 + (wr * 8 + j * 4 + m) * 1024 + rd);
        if (notlast) STAGE(kt + 1, p);
        __builtin_amdgcn_s_barrier();
        __builtin_amdgcn_sched_barrier(0);
        __builtin_amdgcn_s_setprio(1);
#pragma unroll
        for (int m = 0; m < 4; ++m)
#pragma unroll
          for (int n = 0; n < 4; ++n)
            acc[(j * 4 + m) * 4 + n] = __builtin_amdgcn_mfma_f32_16x16x32_bf16(
                afr[m], keep[n], acc[(j * 4 + m) * 4 + n], 0, 0, 0);
        __builtin_amdgcn_s_setprio(0);
      } else {
        bf16x8 bfr[2];
        if (j == 0)
#pragma unroll
          for (int m = 0; m < 4; ++m)
            keep[m] = *reinterpret_cast<const bf16x8*>(bufA + s * AHALF + (wr * 4 + m) * 1024 + rd);
#pragma unroll
        for (int nn = 0; nn < 2; ++nn)
          bfr[nn] = *reinterpret_cast<const bf16x8*>(bufB + s * 16384 + (wc * 4 + j * 2 + nn) * 1024 + rd);
        if (notlast) STAGE(kt + 1, p);
        __builtin_amdgcn_s_barrier();
        __builtin_amdgcn_sched_barrier(0);
        __builtin_amdgcn_s_setprio(1);
#pragma unroll
        for (int m = 0; m < 4; ++m)
#pragma unroll
          for (int nn = 0; nn < 2; ++nn)
            acc[m * 4 + j * 2 + nn] = __builtin_amdgcn_mfma_f32_16x16x32_bf16(
                keep[m], bfr[nn], acc[m * 4 + j * 2 + nn], 0, 0, 0);
        __builtin_amdgcn_s_setprio(0);
      }
      if (p == 1 || p == 3) {
        if (notlast) {
          if constexpr (GEOM == 0) asm volatile("s_waitcnt vmcnt(4)" ::: "memory");
          else asm volatile("s_waitcnt vmcnt(3)" ::: "memory");
        } else {
          asm volatile("s_waitcnt vmcnt(0)" ::: "memory");
        }
      }
      __builtin_amdgcn_s_barrier();
      __builtin_amdgcn_sched_barrier(0);
    }
  }
}

// ---------------- QKV projection: verbatim R2 (validated) ----------------
__global__ __launch_bounds__(512, 2) void proj8_kernel(
    const u16* __restrict__ A, const u16* __restrict__ Bm,
    const float* __restrict__ bq, const float* __restrict__ bk,
    const float* __restrict__ bvv, u16* __restrict__ QK, u16* __restrict__ Vt) {
  extern __shared__ char smem[];
  constexpr int NT = 16;
  const int tid = threadIdx.x;
  const int wave = tid >> 6, lane = tid & 63;
  const int wr = wave >> 2, wc = wave & 3;
  const int tileM = blockIdx.x * 256;
  const int tileN = blockIdx.y * 256;
  const int fr = lane & 15, fg = lane >> 4;
  const int rd_inner = (fr * 64 + fg * 16) ^ (((fr >> 3) & 1) << 5);
  const int li = (lane * 16) ^ ((lane >> 5) << 5);
  const int sr = li >> 6, sc2 = li & 63;
  const int rowA0 = wave * 16 + sr;
  const int rowA1 = 128 + wave * 16 + sr;
  const char* Ab = (const char*)A + (size_t)tileM * 2048;
  const char* Bb = (const char*)Bm + (size_t)tileN * 2048;

  auto STAGE = [&](int kt, int p) {
    const int isB = p & 1, s = p >> 1;
    char* ldsHalf = smem + (kt & 1) * 65536 + isB * 32768 + s * 16384;
    const char* gb = isB ? Bb : Ab;
    const int colOff = kt * 128 + s * 64;
    const char* g0 = gb + (size_t)rowA0 * 2048 + colOff + sc2;
    const char* g1 = gb + (size_t)rowA1 * 2048 + colOff + sc2;
    __builtin_amdgcn_global_load_lds(
        (const __attribute__((address_space(1))) void*)g0,
        (__attribute__((address_space(3))) void*)(ldsHalf + wave * 1024), 16, 0, 0);
    __builtin_amdgcn_global_load_lds(
        (const __attribute__((address_space(1))) void*)g1,
        (__attribute__((address_space(3))) void*)(ldsHalf + 8192 + wave * 1024), 16, 0, 0);
  };

#pragma unroll
  for (int p = 0; p < 4; ++p) STAGE(0, p);
  asm volatile("s_waitcnt vmcnt(4)" ::: "memory");
  __builtin_amdgcn_s_barrier();
  __builtin_amdgcn_sched_barrier(0);

  f32x4 acc[8][4] = {};
  bf16x8 bfr[4];

  for (int kt = 0; kt < NT; ++kt) {
    const char* bufA = smem + (kt & 1) * 65536;
    const char* bufB = bufA + 32768;
    const bool notlast = (kt + 1 < NT);
#pragma unroll
    for (int p = 0; p < 4; ++p) {
      const int s = p >> 1, j = p & 1;
      bf16x8 afr[4];
      if (j == 0) {
#pragma unroll
        for (int n = 0; n < 4; ++n)
          bfr[n] = *reinterpret_cast<const bf16x8*>(bufB + s * 16384 +
                                                    (wc * 4 + n) * 1024 + rd_inner);
      }
#pragma unroll
      for (int m = 0; m < 4; ++m)
        afr[m] = *reinterpret_cast<const bf16x8*>(bufA + s * 16384 +
                                                  (wr * 8 + j * 4 + m) * 1024 + rd_inner);
      if (notlast) STAGE(kt + 1, p);
      __builtin_amdgcn_s_barrier();
      __builtin_amdgcn_sched_barrier(0);
      __builtin_amdgcn_s_setprio(1);
#pragma unroll
      for (int m = 0; m < 4; ++m)
#pragma unroll
        for (int n = 0; n < 4; ++n)
          acc[j * 4 + m][n] = __builtin_amdgcn_mfma_f32_16x16x32_bf16(
              afr[m], bfr[n], acc[j * 4 + m][n], 0, 0, 0);
      __builtin_amdgcn_s_setprio(0);
      if (p == 1 || p == 3) {
        if (notlast) asm volatile("s_waitcnt vmcnt(4)" ::: "memory");
        else asm volatile("s_waitcnt vmcnt(0)" ::: "memory");
      }
      __builtin_amdgcn_s_barrier();
      __builtin_amdgcn_sched_barrier(0);
    }
  }

  const int w = blockIdx.y >> 2;
  const float* bias = (w == 0) ? bq : (w == 1) ? bk : bvv;
  if (w < 2) {
    u16* O = QK + (size_t)w * 8388608;
#pragma unroll
    for (int mi = 0; mi < 8; ++mi) {
      const int r0 = tileM + wr * 128 + mi * 16 + fg * 4;
#pragma unroll
      for (int n = 0; n < 4; ++n) {
        const int cw = (tileN + wc * 64 + n * 16 + fr) & 1023;
        const float bi = bias[cw];
#pragma unroll
        for (int jj = 0; jj < 4; ++jj)
          O[(size_t)(r0 + jj) * 1024 + cw] = f2b(acc[mi][n][jj] + bi);
      }
    }
  } else {
#pragma unroll
    for (int mi = 0; mi < 8; ++mi) {
      const int r0 = tileM + wr * 128 + mi * 16 + fg * 4;
      const int b = r0 >> 11, s0 = r0 & 2047;
#pragma unroll
      for (int n = 0; n < 4; ++n) {
        const int cw = (tileN + wc * 64 + n * 16 + fr) & 1023;
        const float bi = bias[cw];
        ushort4 u = make_ushort4(f2b(acc[mi][n][0] + bi), f2b(acc[mi][n][1] + bi),
                                 f2b(acc[mi][n][2] + bi), f2b(acc[mi][n][3] + bi));
        *reinterpret_cast<ushort4*>(&Vt[(size_t)b * 2097152 + (size_t)cw * 2048 + s0]) = u;
      }
    }
  }
}

// ---------------- sc: P~ = exp(Q K^T / 32) (bf16) + row-sum partials ----------------
// grid (8,8,4): tileM/tileN 256, z = batch. rowpart[by][z][2048] fp32, plain stores.
__global__ __launch_bounds__(512, 2) void sc8_kernel(const u16* __restrict__ Qb,
                                                     const u16* __restrict__ Kb,
                                                     u16* __restrict__ P,
                                                     float* __restrict__ rowpart) {
  extern __shared__ char smem[];
  const int z = blockIdx.z;
  const int tileM = blockIdx.x * 256, tileN = blockIdx.y * 256;
  f32x4 acc[32] = {};
  core8<0, 16>((const char*)Qb + (size_t)z * 4194304 + (size_t)tileM * 2048,
               (const char*)Kb + (size_t)z * 4194304 + (size_t)tileN * 2048, 2048, 2048,
               smem, acc);
  const int tid = threadIdx.x;
  const int wave = tid >> 6, lane = tid & 63;
  const int wr = wave >> 2, wc = wave & 3, fr = lane & 15, fg = lane >> 4;
  float* rs = (float*)smem;  // [4][256], safe: core8 ends with full barrier
  u16* Po = P + (size_t)z * 4194304 + (size_t)tileM * 2048 + tileN;
#pragma unroll
  for (int mi = 0; mi < 8; ++mi) {
#pragma unroll
    for (int jj = 0; jj < 4; ++jj) {
      const int rl = wr * 128 + mi * 16 + fg * 4 + jj;
      float part = 0.f;
#pragma unroll
      for (int n = 0; n < 4; ++n) {
        float e = __expf(acc[mi * 4 + n][jj] * 0.03125f);
        part += e;
        Po[(size_t)rl * 2048 + wc * 64 + n * 16 + fr] = f2b(e);
      }
      part += __shfl_xor(part, 1);
      part += __shfl_xor(part, 2);
      part += __shfl_xor(part, 4);
      part += __shfl_xor(part, 8);
      if (fr == 0) rs[wc * 256 + rl] = part;
    }
  }
  __syncthreads();
  if (tid < 256) {
    float s = rs[tid] + rs[256 + tid] + rs[512 + tid] + rs[768 + tid];
    rowpart[(size_t)blockIdx.y * 8192 + z * 2048 + tileM + tid] = s;
  }
}

// 8192 rows: sum 8 partials -> 1/rowsum
__global__ __launch_bounds__(256) void rsum_kernel(const float* __restrict__ rowpart,
                                                   float* __restrict__ rowinv) {
  const int i = blockIdx.x * 256 + threadIdx.x;
  float s = 0.f;
#pragma unroll
  for (int t = 0; t < 8; ++t) s += rowpart[t * 8192 + i];
  rowinv[i] = 1.0f / s;
}

// ---------------- pv: out = (P~ Vt^T) * rowinv ----------------
// grid (16,4,4): tileM = bx*128, tileN = by*256, z = batch. GEOM 1, NT=32.
__global__ __launch_bounds__(512, 2) void pv8_kernel(const u16* __restrict__ P,
                                                     const u16* __restrict__ Vt,
                                                     const float* __restrict__ rowinv,
                                                     float* __restrict__ out) {
  extern __shared__ char smem[];
  const int z = blockIdx.z;
  const int tileM = blockIdx.x * 128, tileN = blockIdx.y * 256;
  f32x4 acc[16] = {};
  core8<1, 32>((const char*)P + (size_t)z * 8388608 + (size_t)tileM * 4096,
               (const char*)Vt + (size_t)z * 4194304 + (size_t)tileN * 4096, 4096, 4096,
               smem, acc);
  const int tid = threadIdx.x;
  const int wave = tid >> 6, lane = tid & 63;
  const int wr = wave >> 2, wc = wave & 3, fr = lane & 15, fg = lane >> 4;
  float* O = out + (size_t)z * 2097152;
  const float* ri = rowinv + z * 2048 + tileM;
#pragma unroll
  for (int mi = 0; mi < 4; ++mi) {
#pragma unroll
    for (int jj = 0; jj < 4; ++jj) {
      const int r = wr * 64 + mi * 16 + fg * 4 + jj;
      const float inv = ri[r];
#pragma unroll
      for (int n = 0; n < 4; ++n)
        O[(size_t)(tileM + r) * 1024 + tileN + wc * 64 + n * 16 + fr] =
            acc[mi * 4 + n][jj] * inv;
    }
  }
}

extern "C" void kernel_launch(void* const* d_in, const int* in_sizes, int n_in,
                              void* d_out, int out_size, void* d_ws, size_t ws_size,
                              hipStream_t stream) {
  if (ws_size < ((size_t)72 << 20)) return;
  const float* x = (const float*)d_in[0];
  const float* Wq = (const float*)d_in[1];
  const float* bq = (const float*)d_in[2];
  const float* Wk = (const float*)d_in[3];
  const float* bk = (const float*)d_in[4];
  const float* Wv = (const float*)d_in[5];
  const float* bv = (const float*)d_in[6];
  char* ws = (char*)d_ws;
  u16* xb = (u16*)(ws);                       // [0,16M); later P~ [4][2048][2048]
  u16* Pb = (u16*)(ws);
  u16* Qb = (u16*)(ws + ((size_t)16 << 20));
  u16* Kb = (u16*)(ws + ((size_t)32 << 20));
  u16* Vt = (u16*)(ws + ((size_t)48 << 20));
  u16* Wb = (u16*)(ws + ((size_t)64 << 20));
  float* rowpart = (float*)(ws + ((size_t)70 << 20));           // 256 KiB
  float* rowinv = (float*)(ws + ((size_t)70 << 20) + 262144);   // 32 KiB
  float* out = (float*)d_out;

  (void)hipFuncSetAttribute((const void*)proj8_kernel,
                            hipFuncAttributeMaxDynamicSharedMemorySize, 131072);
  (void)hipFuncSetAttribute((const void*)sc8_kernel,
                            hipFuncAttributeMaxDynamicSharedMemorySize, 131072);
  (void)hipFuncSetAttribute((const void*)pv8_kernel,
                            hipFuncAttributeMaxDynamicSharedMemorySize, 98304);

  cast_x_kernel<<<8192, 256, 0, stream>>>(x, xb, 2097152);
  cast_w_kernel<<<3072, 256, 0, stream>>>(Wq, Wk, Wv, Wb);

  proj8_kernel<<<dim3(32, 12), 512, 131072, stream>>>(xb, Wb, bq, bk, bv, Qb, Vt);

  sc8_kernel<<<dim3(8, 8, 4), 512, 131072, stream>>>(Qb, Kb, Pb, rowpart);
  rsum_kernel<<<32, 256, 0, stream>>>(rowpart, rowinv);
  pv8_kernel<<<dim3(16, 4, 4), 512, 98304, stream>>>(Pb, Vt, rowinv, out);
}

// Round 5
// 160.789 us; speedup vs baseline: 2.5700x; 1.0072x over previous
//
#include <hip/hip_runtime.h>

// SelfAttention: B=4, S=2048, D=1024, fp32 in/out. bf16 MFMA, fp32 accum.
// R4: deep-prefetch 8-phase core (stage stream shifted +2 phases; steady
// vmcnt(8) GEOM0 / vmcnt(6) GEOM1 -> 4 phases of load-latency slack).
// Structure otherwise identical to R3:
//   proj: 256x256 8-phase, grid 32x12 (384 blocks, 2 rounds)
//   sc:   256x256 8-phase, grid 8x8x4 = 256 blocks, P~=exp(QK^T/32) + rowsums
//   pv:   128x256 8-phase, grid 16x4x4 = 256 blocks, multiplies 1/rowsum
// ws layout (MiB):
//   [0,16)   x_bf16 (proj) -> P~ bf16 [4][2048][2048]
//   [16,32)  Q bf16   [32,48) K bf16   [48,64) Vt bf16 [4][1024][2048]
//   [64,70)  Wq|Wk|Wv bf16
//   [70,+256K) rowpart fp32 [8][4][2048]  then rowinv fp32 [4][2048]

typedef __bf16 bf16x8 __attribute__((ext_vector_type(8)));
typedef float f32x4 __attribute__((ext_vector_type(4)));
typedef unsigned short u16;

__device__ __forceinline__ u16 f2b(float f) {
  union { float f; unsigned u; } a; a.f = f;
  unsigned r = a.u + 0x7fffu + ((a.u >> 16) & 1u);  // RNE
  return (u16)(r >> 16);
}

__global__ __launch_bounds__(256) void cast_x_kernel(const float* __restrict__ in,
                                                     u16* __restrict__ out, int n4) {
  int i = blockIdx.x * 256 + threadIdx.x;
  if (i < n4) {
    float4 v = reinterpret_cast<const float4*>(in)[i];
    reinterpret_cast<ushort4*>(out)[i] =
        make_ushort4(f2b(v.x), f2b(v.y), f2b(v.z), f2b(v.w));
  }
}

__global__ __launch_bounds__(256) void cast_w_kernel(const float* __restrict__ Wq,
                                                     const float* __restrict__ Wk,
                                                     const float* __restrict__ Wv,
                                                     u16* __restrict__ out) {
  const int b = blockIdx.x;
  const int w = b >> 10;
  const float* src = (w == 0) ? Wq : (w == 1) ? Wk : Wv;
  const int i = (b & 1023) * 256 + threadIdx.x;
  float4 v = reinterpret_cast<const float4*>(src)[i];
  reinterpret_cast<ushort4*>(out + (size_t)w * 1048576)[i] =
      make_ushort4(f2b(v.x), f2b(v.y), f2b(v.z), f2b(v.w));
}

// ---------------- deep-prefetch 8-phase core ----------------
// GEOM 0: BM=256,BN=256 (acc f32x4[32]); GEOM 1: BM=128,BN=256 (acc f32x4[16]).
// 8 waves: wr=wave>>2 (M), wc=wave&3 (N). BK=64, NT K-tiles. lda/ldb in BYTES.
// Stage stream: phase g issues S(g+6); steady wait vmcnt(8)/(6) at p1,p3 ends.
template <int GEOM, int NT>
__device__ __forceinline__ void core8(const char* __restrict__ Ab,
                                      const char* __restrict__ Bb, int lda, int ldb,
                                      char* smem, f32x4* acc) {
  constexpr int LDSBUF = GEOM ? 49152 : 65536;
  constexpr int BOFF = GEOM ? 16384 : 32768;
  constexpr int AHALF = GEOM ? 8192 : 16384;
  const int tid = threadIdx.x;
  const int wave = tid >> 6, lane = tid & 63;
  const int wr = wave >> 2, wc = wave & 3;
  const int fr = lane & 15, fg = lane >> 4;
  const int rd = (fr * 64 + fg * 16) ^ (((fr >> 3) & 1) << 5);
  const int li = (lane * 16) ^ ((lane >> 5) << 5);
  const int sr = li >> 6, sc2 = li & 63;

  auto STAGE = [&](int kt, int p) {
    const int isB = p & 1, s = p >> 1;
    char* lds = smem + (kt & 1) * LDSBUF + (isB ? BOFF + s * 16384 : s * AHALF);
    const char* gb = isB ? Bb : Ab;
    const int ldx = isB ? ldb : lda;
    const int colOff = kt * 128 + s * 64 + sc2;
    __builtin_amdgcn_global_load_lds(
        (const __attribute__((address_space(1))) void*)(gb + (size_t)(wave * 16 + sr) * ldx + colOff),
        (__attribute__((address_space(3))) void*)(lds + wave * 1024), 16, 0, 0);
    if (isB || GEOM == 0)
      __builtin_amdgcn_global_load_lds(
          (const __attribute__((address_space(1))) void*)(gb + (size_t)((8 + wave) * 16 + sr) * ldx + colOff),
          (__attribute__((address_space(3))) void*)(lds + 8192 + wave * 1024), 16, 0, 0);
  };

  // prologue: S(0..5) = tile0 all 4 halves + tile1 halves 0,1
#pragma unroll
  for (int p = 0; p < 4; ++p) STAGE(0, p);
  STAGE(1, 0);
  STAGE(1, 1);
  if constexpr (GEOM == 0) asm volatile("s_waitcnt vmcnt(8)" ::: "memory");
  else asm volatile("s_waitcnt vmcnt(6)" ::: "memory");
  __builtin_amdgcn_s_barrier();
  __builtin_amdgcn_sched_barrier(0);

  bf16x8 keep[4];  // GEOM0: B frags held across j; GEOM1: A frags held across j
  for (int kt = 0; kt < NT; ++kt) {
    const char* bufA = smem + (kt & 1) * LDSBUF;
    const char* bufB = bufA + BOFF;
#pragma unroll
    for (int p = 0; p < 4; ++p) {
      const int s = p >> 1, j = p & 1;
      if constexpr (GEOM == 0) {
        bf16x8 afr[4];
        if (j == 0)
#pragma unroll
          for (int n = 0; n < 4; ++n)
            keep[n] = *reinterpret_cast<const bf16x8*>(bufB + s * 16384 + (wc * 4 + n) * 1024 + rd);
#pragma unroll
        for (int m = 0; m < 4; ++m)
          afr[m] = *reinterpret_cast<const bf16x8*>(bufA + s * 16384 + (wr * 8 + j * 4 + m) * 1024 + rd);
        if (p < 2) { if (kt + 1 < NT) STAGE(kt + 1, p + 2); }
        else       { if (kt + 2 < NT) STAGE(kt + 2, p - 2); }
        __builtin_amdgcn_s_barrier();
        __builtin_amdgcn_sched_barrier(0);
        __builtin_amdgcn_s_setprio(1);
#pragma unroll
        for (int m = 0; m < 4; ++m)
#pragma unroll
          for (int n = 0; n < 4; ++n)
            acc[(j * 4 + m) * 4 + n] = __builtin_amdgcn_mfma_f32_16x16x32_bf16(
                afr[m], keep[n], acc[(j * 4 + m) * 4 + n], 0, 0, 0);
        __builtin_amdgcn_s_setprio(0);
      } else {
        bf16x8 bfr[2];
        if (j == 0)
#pragma unroll
          for (int m = 0; m < 4; ++m)
            keep[m] = *reinterpret_cast<const bf16x8*>(bufA + s * AHALF + (wr * 4 + m) * 1024 + rd);
#pragma unroll
        for (int nn = 0; nn < 2; ++nn)
          bfr[nn] = *reinterpret_cast<const bf16x8*>(bufB + s * 16384 + (wc * 4 + j * 2 + nn) * 1024 + rd);
        if (p < 2) { if (kt + 1 < NT) STAGE(kt + 1, p + 2); }
        else       { if (kt + 2 < NT) STAGE(kt + 2, p - 2); }
        __builtin_amdgcn_s_barrier();
        __builtin_amdgcn_sched_barrier(0);
        __builtin_amdgcn_s_setprio(1);
#pragma unroll
        for (int m = 0; m < 4; ++m)
#pragma unroll
          for (int nn = 0; nn < 2; ++nn)
            acc[m * 4 + j * 2 + nn] = __builtin_amdgcn_mfma_f32_16x16x32_bf16(
                keep[m], bfr[nn], acc[m * 4 + j * 2 + nn], 0, 0, 0);
        __builtin_amdgcn_s_setprio(0);
      }
      // counted waits: steady vmcnt(8)/(6); tails derived (see R4 notes)
      if (p == 1) {
        if (kt < NT - 1) {
          if constexpr (GEOM == 0) asm volatile("s_waitcnt vmcnt(8)" ::: "memory");
          else asm volatile("s_waitcnt vmcnt(6)" ::: "memory");
        } else {
          asm volatile("s_waitcnt vmcnt(0)" ::: "memory");
        }
      } else if (p == 3) {
        if (kt < NT - 2) {
          if constexpr (GEOM == 0) asm volatile("s_waitcnt vmcnt(8)" ::: "memory");
          else asm volatile("s_waitcnt vmcnt(6)" ::: "memory");
        } else if (kt == NT - 2) {
          if constexpr (GEOM == 0) asm volatile("s_waitcnt vmcnt(4)" ::: "memory");
          else asm volatile("s_waitcnt vmcnt(3)" ::: "memory");
        }
      }
      __builtin_amdgcn_s_barrier();
      __builtin_amdgcn_sched_barrier(0);
    }
  }
}

// ---------------- QKV projection (core8<0,16>) ----------------
// A = xb [8192][1024], B = Wb [3072][1024]. w = by>>2: 0/1 -> Q/K; 2 -> Vt transposed.
__global__ __launch_bounds__(512, 2) void proj8_kernel(
    const u16* __restrict__ A, const u16* __restrict__ Bm,
    const float* __restrict__ bq, const float* __restrict__ bk,
    const float* __restrict__ bvv, u16* __restrict__ QK, u16* __restrict__ Vt) {
  extern __shared__ char smem[];
  const int tileM = blockIdx.x * 256, tileN = blockIdx.y * 256;
  f32x4 acc[32] = {};
  core8<0, 16>((const char*)A + (size_t)tileM * 2048,
               (const char*)Bm + (size_t)tileN * 2048, 2048, 2048, smem, acc);
  const int tid = threadIdx.x;
  const int wave = tid >> 6, lane = tid & 63;
  const int wr = wave >> 2, wc = wave & 3, fr = lane & 15, fg = lane >> 4;
  const int w = blockIdx.y >> 2;  // weight id (256-col tiles never straddle weights)
  const float* bias = (w == 0) ? bq : (w == 1) ? bk : bvv;
  if (w < 2) {
    u16* O = QK + (size_t)w * 8388608;
#pragma unroll
    for (int mi = 0; mi < 8; ++mi) {
      const int r0 = tileM + wr * 128 + mi * 16 + fg * 4;
#pragma unroll
      for (int n = 0; n < 4; ++n) {
        const int cw = (tileN + wc * 64 + n * 16 + fr) & 1023;
        const float bi = bias[cw];
#pragma unroll
        for (int jj = 0; jj < 4; ++jj)
          O[(size_t)(r0 + jj) * 1024 + cw] = f2b(acc[mi * 4 + n][jj] + bi);
      }
    }
  } else {
#pragma unroll
    for (int mi = 0; mi < 8; ++mi) {
      const int r0 = tileM + wr * 128 + mi * 16 + fg * 4;
      const int b = r0 >> 11, s0 = r0 & 2047;
#pragma unroll
      for (int n = 0; n < 4; ++n) {
        const int cw = (tileN + wc * 64 + n * 16 + fr) & 1023;
        const float bi = bias[cw];
        ushort4 u = make_ushort4(f2b(acc[mi * 4 + n][0] + bi), f2b(acc[mi * 4 + n][1] + bi),
                                 f2b(acc[mi * 4 + n][2] + bi), f2b(acc[mi * 4 + n][3] + bi));
        *reinterpret_cast<ushort4*>(&Vt[(size_t)b * 2097152 + (size_t)cw * 2048 + s0]) = u;
      }
    }
  }
}

// ---------------- sc: P~ = exp(Q K^T / 32) (bf16) + row-sum partials ----------------
__global__ __launch_bounds__(512, 2) void sc8_kernel(const u16* __restrict__ Qb,
                                                     const u16* __restrict__ Kb,
                                                     u16* __restrict__ P,
                                                     float* __restrict__ rowpart) {
  extern __shared__ char smem[];
  const int z = blockIdx.z;
  const int tileM = blockIdx.x * 256, tileN = blockIdx.y * 256;
  f32x4 acc[32] = {};
  core8<0, 16>((const char*)Qb + (size_t)z * 4194304 + (size_t)tileM * 2048,
               (const char*)Kb + (size_t)z * 4194304 + (size_t)tileN * 2048, 2048, 2048,
               smem, acc);
  const int tid = threadIdx.x;
  const int wave = tid >> 6, lane = tid & 63;
  const int wr = wave >> 2, wc = wave & 3, fr = lane & 15, fg = lane >> 4;
  float* rs = (float*)smem;  // [4][256]; safe: core8 ends with full barrier
  u16* Po = P + (size_t)z * 4194304 + (size_t)tileM * 2048 + tileN;
#pragma unroll
  for (int mi = 0; mi < 8; ++mi) {
#pragma unroll
    for (int jj = 0; jj < 4; ++jj) {
      const int rl = wr * 128 + mi * 16 + fg * 4 + jj;
      float part = 0.f;
#pragma unroll
      for (int n = 0; n < 4; ++n) {
        float e = __expf(acc[mi * 4 + n][jj] * 0.03125f);
        part += e;
        Po[(size_t)rl * 2048 + wc * 64 + n * 16 + fr] = f2b(e);
      }
      part += __shfl_xor(part, 1);
      part += __shfl_xor(part, 2);
      part += __shfl_xor(part, 4);
      part += __shfl_xor(part, 8);
      if (fr == 0) rs[wc * 256 + rl] = part;
    }
  }
  __syncthreads();
  if (tid < 256) {
    float s = rs[tid] + rs[256 + tid] + rs[512 + tid] + rs[768 + tid];
    rowpart[(size_t)blockIdx.y * 8192 + z * 2048 + tileM + tid] = s;
  }
}

__global__ __launch_bounds__(256) void rsum_kernel(const float* __restrict__ rowpart,
                                                   float* __restrict__ rowinv) {
  const int i = blockIdx.x * 256 + threadIdx.x;
  float s = 0.f;
#pragma unroll
  for (int t = 0; t < 8; ++t) s += rowpart[t * 8192 + i];
  rowinv[i] = 1.0f / s;
}

// ---------------- pv: out = (P~ Vt^T) * rowinv ----------------
__global__ __launch_bounds__(512, 2) void pv8_kernel(const u16* __restrict__ P,
                                                     const u16* __restrict__ Vt,
                                                     const float* __restrict__ rowinv,
                                                     float* __restrict__ out) {
  extern __shared__ char smem[];
  const int z = blockIdx.z;
  const int tileM = blockIdx.x * 128, tileN = blockIdx.y * 256;
  f32x4 acc[16] = {};
  core8<1, 32>((const char*)P + (size_t)z * 8388608 + (size_t)tileM * 4096,
               (const char*)Vt + (size_t)z * 4194304 + (size_t)tileN * 4096, 4096, 4096,
               smem, acc);
  const int tid = threadIdx.x;
  const int wave = tid >> 6, lane = tid & 63;
  const int wr = wave >> 2, wc = wave & 3, fr = lane & 15, fg = lane >> 4;
  float* O = out + (size_t)z * 2097152;
  const float* ri = rowinv + z * 2048 + tileM;
#pragma unroll
  for (int mi = 0; mi < 4; ++mi) {
#pragma unroll
    for (int jj = 0; jj < 4; ++jj) {
      const int r = wr * 64 + mi * 16 + fg * 4 + jj;
      const float inv = ri[r];
#pragma unroll
      for (int n = 0; n < 4; ++n)
        O[(size_t)(tileM + r) * 1024 + tileN + wc * 64 + n * 16 + fr] =
            acc[mi * 4 + n][jj] * inv;
    }
  }
}

extern "C" void kernel_launch(void* const* d_in, const int* in_sizes, int n_in,
                              void* d_out, int out_size, void* d_ws, size_t ws_size,
                              hipStream_t stream) {
  if (ws_size < ((size_t)72 << 20)) return;
  const float* x = (const float*)d_in[0];
  const float* Wq = (const float*)d_in[1];
  const float* bq = (const float*)d_in[2];
  const float* Wk = (const float*)d_in[3];
  const float* bk = (const float*)d_in[4];
  const float* Wv = (const float*)d_in[5];
  const float* bv = (const float*)d_in[6];
  char* ws = (char*)d_ws;
  u16* xb = (u16*)(ws);                       // [0,16M); later P~ [4][2048][2048]
  u16* Pb = (u16*)(ws);
  u16* Qb = (u16*)(ws + ((size_t)16 << 20));
  u16* Kb = (u16*)(ws + ((size_t)32 << 20));
  u16* Vt = (u16*)(ws + ((size_t)48 << 20));
  u16* Wb = (u16*)(ws + ((size_t)64 << 20));
  float* rowpart = (float*)(ws + ((size_t)70 << 20));           // 256 KiB
  float* rowinv = (float*)(ws + ((size_t)70 << 20) + 262144);   // 32 KiB
  float* out = (float*)d_out;

  (void)hipFuncSetAttribute((const void*)proj8_kernel,
                            hipFuncAttributeMaxDynamicSharedMemorySize, 131072);
  (void)hipFuncSetAttribute((const void*)sc8_kernel,
                            hipFuncAttributeMaxDynamicSharedMemorySize, 131072);
  (void)hipFuncSetAttribute((const void*)pv8_kernel,
                            hipFuncAttributeMaxDynamicSharedMemorySize, 98304);

  cast_x_kernel<<<8192, 256, 0, stream>>>(x, xb, 2097152);
  cast_w_kernel<<<3072, 256, 0, stream>>>(Wq, Wk, Wv, Wb);

  proj8_kernel<<<dim3(32, 12), 512, 131072, stream>>>(xb, Wb, bq, bk, bv, Qb, Vt);

  sc8_kernel<<<dim3(8, 8, 4), 512, 131072, stream>>>(Qb, Kb, Pb, rowpart);
  rsum_kernel<<<32, 256, 0, stream>>>(rowpart, rowinv);
  pv8_kernel<<<dim3(16, 4, 4), 512, 98304, stream>>>(Pb, Vt, rowinv, out);
}

// Round 6
// 155.662 us; speedup vs baseline: 2.6546x; 1.0329x over previous
//
#include <hip/hip_runtime.h>

// SelfAttention: B=4, S=2048, D=1024, fp32 in/out. bf16 MFMA, fp32 accum.
// R5: proj -> GEOM1 128x256, grid 64x12 = 768 blocks = exactly 3 full rounds
// (R2/R4 proj was 384 blocks = 1.5 rounds = 75% fill). Casts merged into one
// dispatch. rsum kernel folded into pv8 prologue (rowinv in LDS). core8 is
// the R4-validated deep-prefetch 8-phase counted-vmcnt schedule, untouched.
//   proj: 128x256 8-phase GEOM1, grid (64,12) = 768 blocks
//   sc:   256x256 8-phase GEOM0, grid (8,8,4) = 256 blocks, P~=exp(QK^T/32)+rowsums
//   pv:   128x256 8-phase GEOM1, grid (16,4,4) = 256 blocks, * 1/rowsum
// ws layout (MiB):
//   [0,16)   x_bf16 (proj) -> P~ bf16 [4][2048][2048]
//   [16,32)  Q bf16   [32,48) K bf16   [48,64) Vt bf16 [4][1024][2048]
//   [64,70)  Wq|Wk|Wv bf16
//   [70,+256K) rowpart fp32 [8][4][2048]

typedef __bf16 bf16x8 __attribute__((ext_vector_type(8)));
typedef float f32x4 __attribute__((ext_vector_type(4)));
typedef unsigned short u16;

__device__ __forceinline__ u16 f2b(float f) {
  union { float f; unsigned u; } a; a.f = f;
  unsigned r = a.u + 0x7fffu + ((a.u >> 16) & 1u);  // RNE
  return (u16)(r >> 16);
}

// blocks [0,8192): x (2097152 float4s). blocks [8192,11264): Wq|Wk|Wv.
__global__ __launch_bounds__(256) void cast_all_kernel(const float* __restrict__ x,
                                                       const float* __restrict__ Wq,
                                                       const float* __restrict__ Wk,
                                                       const float* __restrict__ Wv,
                                                       u16* __restrict__ xb,
                                                       u16* __restrict__ Wb) {
  int b = blockIdx.x;
  if (b < 8192) {
    const int i = b * 256 + threadIdx.x;
    float4 v = reinterpret_cast<const float4*>(x)[i];
    reinterpret_cast<ushort4*>(xb)[i] =
        make_ushort4(f2b(v.x), f2b(v.y), f2b(v.z), f2b(v.w));
  } else {
    b -= 8192;
    const int w = b >> 10;
    const float* src = (w == 0) ? Wq : (w == 1) ? Wk : Wv;
    const int i = (b & 1023) * 256 + threadIdx.x;
    float4 v = reinterpret_cast<const float4*>(src)[i];
    reinterpret_cast<ushort4*>(Wb + (size_t)w * 1048576)[i] =
        make_ushort4(f2b(v.x), f2b(v.y), f2b(v.z), f2b(v.w));
  }
}

// ---------------- deep-prefetch 8-phase core (R4, validated) ----------------
// GEOM 0: BM=256,BN=256 (acc f32x4[32]); GEOM 1: BM=128,BN=256 (acc f32x4[16]).
// 8 waves: wr=wave>>2 (M), wc=wave&3 (N). BK=64, NT K-tiles. lda/ldb in BYTES.
// Stage stream: phase g issues S(g+6); steady wait vmcnt(8)/(6) at p1,p3 ends.
template <int GEOM, int NT>
__device__ __forceinline__ void core8(const char* __restrict__ Ab,
                                      const char* __restrict__ Bb, int lda, int ldb,
                                      char* smem, f32x4* acc) {
  constexpr int LDSBUF = GEOM ? 49152 : 65536;
  constexpr int BOFF = GEOM ? 16384 : 32768;
  constexpr int AHALF = GEOM ? 8192 : 16384;
  const int tid = threadIdx.x;
  const int wave = tid >> 6, lane = tid & 63;
  const int wr = wave >> 2, wc = wave & 3;
  const int fr = lane & 15, fg = lane >> 4;
  const int rd = (fr * 64 + fg * 16) ^ (((fr >> 3) & 1) << 5);
  const int li = (lane * 16) ^ ((lane >> 5) << 5);
  const int sr = li >> 6, sc2 = li & 63;

  auto STAGE = [&](int kt, int p) {
    const int isB = p & 1, s = p >> 1;
    char* lds = smem + (kt & 1) * LDSBUF + (isB ? BOFF + s * 16384 : s * AHALF);
    const char* gb = isB ? Bb : Ab;
    const int ldx = isB ? ldb : lda;
    const int colOff = kt * 128 + s * 64 + sc2;
    __builtin_amdgcn_global_load_lds(
        (const __attribute__((address_space(1))) void*)(gb + (size_t)(wave * 16 + sr) * ldx + colOff),
        (__attribute__((address_space(3))) void*)(lds + wave * 1024), 16, 0, 0);
    if (isB || GEOM == 0)
      __builtin_amdgcn_global_load_lds(
          (const __attribute__((address_space(1))) void*)(gb + (size_t)((8 + wave) * 16 + sr) * ldx + colOff),
          (__attribute__((address_space(3))) void*)(lds + 8192 + wave * 1024), 16, 0, 0);
  };

  // prologue: S(0..5) = tile0 all 4 halves + tile1 halves 0,1
#pragma unroll
  for (int p = 0; p < 4; ++p) STAGE(0, p);
  STAGE(1, 0);
  STAGE(1, 1);
  if constexpr (GEOM == 0) asm volatile("s_waitcnt vmcnt(8)" ::: "memory");
  else asm volatile("s_waitcnt vmcnt(6)" ::: "memory");
  __builtin_amdgcn_s_barrier();
  __builtin_amdgcn_sched_barrier(0);

  bf16x8 keep[4];  // GEOM0: B frags held across j; GEOM1: A frags held across j
  for (int kt = 0; kt < NT; ++kt) {
    const char* bufA = smem + (kt & 1) * LDSBUF;
    const char* bufB = bufA + BOFF;
#pragma unroll
    for (int p = 0; p < 4; ++p) {
      const int s = p >> 1, j = p & 1;
      if constexpr (GEOM == 0) {
        bf16x8 afr[4];
        if (j == 0)
#pragma unroll
          for (int n = 0; n < 4; ++n)
            keep[n] = *reinterpret_cast<const bf16x8*>(bufB + s * 16384 + (wc * 4 + n) * 1024 + rd);
#pragma unroll
        for (int m = 0; m < 4; ++m)
          afr[m] = *reinterpret_cast<const bf16x8*>(bufA + s * 16384 + (wr * 8 + j * 4 + m) * 1024 + rd);
        if (p < 2) { if (kt + 1 < NT) STAGE(kt + 1, p + 2); }
        else       { if (kt + 2 < NT) STAGE(kt + 2, p - 2); }
        __builtin_amdgcn_s_barrier();
        __builtin_amdgcn_sched_barrier(0);
        __builtin_amdgcn_s_setprio(1);
#pragma unroll
        for (int m = 0; m < 4; ++m)
#pragma unroll
          for (int n = 0; n < 4; ++n)
            acc[(j * 4 + m) * 4 + n] = __builtin_amdgcn_mfma_f32_16x16x32_bf16(
                afr[m], keep[n], acc[(j * 4 + m) * 4 + n], 0, 0, 0);
        __builtin_amdgcn_s_setprio(0);
      } else {
        bf16x8 bfr[2];
        if (j == 0)
#pragma unroll
          for (int m = 0; m < 4; ++m)
            keep[m] = *reinterpret_cast<const bf16x8*>(bufA + s * AHALF + (wr * 4 + m) * 1024 + rd);
#pragma unroll
        for (int nn = 0; nn < 2; ++nn)
          bfr[nn] = *reinterpret_cast<const bf16x8*>(bufB + s * 16384 + (wc * 4 + j * 2 + nn) * 1024 + rd);
        if (p < 2) { if (kt + 1 < NT) STAGE(kt + 1, p + 2); }
        else       { if (kt + 2 < NT) STAGE(kt + 2, p - 2); }
        __builtin_amdgcn_s_barrier();
        __builtin_amdgcn_sched_barrier(0);
        __builtin_amdgcn_s_setprio(1);
#pragma unroll
        for (int m = 0; m < 4; ++m)
#pragma unroll
          for (int nn = 0; nn < 2; ++nn)
            acc[m * 4 + j * 2 + nn] = __builtin_amdgcn_mfma_f32_16x16x32_bf16(
                keep[m], bfr[nn], acc[m * 4 + j * 2 + nn], 0, 0, 0);
        __builtin_amdgcn_s_setprio(0);
      }
      if (p == 1) {
        if (kt < NT - 1) {
          if constexpr (GEOM == 0) asm volatile("s_waitcnt vmcnt(8)" ::: "memory");
          else asm volatile("s_waitcnt vmcnt(6)" ::: "memory");
        } else {
          asm volatile("s_waitcnt vmcnt(0)" ::: "memory");
        }
      } else if (p == 3) {
        if (kt < NT - 2) {
          if constexpr (GEOM == 0) asm volatile("s_waitcnt vmcnt(8)" ::: "memory");
          else asm volatile("s_waitcnt vmcnt(6)" ::: "memory");
        } else if (kt == NT - 2) {
          if constexpr (GEOM == 0) asm volatile("s_waitcnt vmcnt(4)" ::: "memory");
          else asm volatile("s_waitcnt vmcnt(3)" ::: "memory");
        }
      }
      __builtin_amdgcn_s_barrier();
      __builtin_amdgcn_sched_barrier(0);
    }
  }
}

// ---------------- QKV projection: GEOM1 128x256, grid (64,12) = 768 blocks ----------------
// A = xb [8192][1024], B = Wb [3072][1024]. w = by>>2: 0/1 -> Q/K; 2 -> Vt transposed.
__global__ __launch_bounds__(512, 2) void proj8_kernel(
    const u16* __restrict__ A, const u16* __restrict__ Bm,
    const float* __restrict__ bq, const float* __restrict__ bk,
    const float* __restrict__ bvv, u16* __restrict__ QK, u16* __restrict__ Vt) {
  extern __shared__ char smem[];
  const int tileM = blockIdx.x * 128, tileN = blockIdx.y * 256;
  f32x4 acc[16] = {};
  core8<1, 16>((const char*)A + (size_t)tileM * 2048,
               (const char*)Bm + (size_t)tileN * 2048, 2048, 2048, smem, acc);
  const int tid = threadIdx.x;
  const int wave = tid >> 6, lane = tid & 63;
  const int wr = wave >> 2, wc = wave & 3, fr = lane & 15, fg = lane >> 4;
  const int w = blockIdx.y >> 2;  // weight id (256-col tiles never straddle weights)
  const float* bias = (w == 0) ? bq : (w == 1) ? bk : bvv;
  if (w < 2) {
    u16* O = QK + (size_t)w * 8388608;
#pragma unroll
    for (int mi = 0; mi < 4; ++mi) {
      const int r0 = tileM + wr * 64 + mi * 16 + fg * 4;
#pragma unroll
      for (int n = 0; n < 4; ++n) {
        const int cw = (tileN + wc * 64 + n * 16 + fr) & 1023;
        const float bi = bias[cw];
#pragma unroll
        for (int jj = 0; jj < 4; ++jj)
          O[(size_t)(r0 + jj) * 1024 + cw] = f2b(acc[mi * 4 + n][jj] + bi);
      }
    }
  } else {
#pragma unroll
    for (int mi = 0; mi < 4; ++mi) {
      const int r0 = tileM + wr * 64 + mi * 16 + fg * 4;
      const int b = r0 >> 11, s0 = r0 & 2047;  // rows r0..r0+3 never straddle a batch
#pragma unroll
      for (int n = 0; n < 4; ++n) {
        const int cw = (tileN + wc * 64 + n * 16 + fr) & 1023;
        const float bi = bias[cw];
        ushort4 u = make_ushort4(f2b(acc[mi * 4 + n][0] + bi), f2b(acc[mi * 4 + n][1] + bi),
                                 f2b(acc[mi * 4 + n][2] + bi), f2b(acc[mi * 4 + n][3] + bi));
        *reinterpret_cast<ushort4*>(&Vt[(size_t)b * 2097152 + (size_t)cw * 2048 + s0]) = u;
      }
    }
  }
}

// ---------------- sc: P~ = exp(Q K^T / 32) (bf16) + row-sum partials ----------------
__global__ __launch_bounds__(512, 2) void sc8_kernel(const u16* __restrict__ Qb,
                                                     const u16* __restrict__ Kb,
                                                     u16* __restrict__ P,
                                                     float* __restrict__ rowpart) {
  extern __shared__ char smem[];
  const int z = blockIdx.z;
  const int tileM = blockIdx.x * 256, tileN = blockIdx.y * 256;
  f32x4 acc[32] = {};
  core8<0, 16>((const char*)Qb + (size_t)z * 4194304 + (size_t)tileM * 2048,
               (const char*)Kb + (size_t)z * 4194304 + (size_t)tileN * 2048, 2048, 2048,
               smem, acc);
  const int tid = threadIdx.x;
  const int wave = tid >> 6, lane = tid & 63;
  const int wr = wave >> 2, wc = wave & 3, fr = lane & 15, fg = lane >> 4;
  float* rs = (float*)smem;  // [4][256]; safe: core8 ends with full barrier
  u16* Po = P + (size_t)z * 4194304 + (size_t)tileM * 2048 + tileN;
#pragma unroll
  for (int mi = 0; mi < 8; ++mi) {
#pragma unroll
    for (int jj = 0; jj < 4; ++jj) {
      const int rl = wr * 128 + mi * 16 + fg * 4 + jj;
      float part = 0.f;
#pragma unroll
      for (int n = 0; n < 4; ++n) {
        float e = __expf(acc[mi * 4 + n][jj] * 0.03125f);
        part += e;
        Po[(size_t)rl * 2048 + wc * 64 + n * 16 + fr] = f2b(e);
      }
      part += __shfl_xor(part, 1);
      part += __shfl_xor(part, 2);
      part += __shfl_xor(part, 4);
      part += __shfl_xor(part, 8);
      if (fr == 0) rs[wc * 256 + rl] = part;
    }
  }
  __syncthreads();
  if (tid < 256) {
    float s = rs[tid] + rs[256 + tid] + rs[512 + tid] + rs[768 + tid];
    rowpart[(size_t)blockIdx.y * 8192 + z * 2048 + tileM + tid] = s;
  }
}

// ---------------- pv: out = (P~ Vt^T) * rowinv (rowinv computed in-kernel) ----------------
__global__ __launch_bounds__(512, 2) void pv8_kernel(const u16* __restrict__ P,
                                                     const u16* __restrict__ Vt,
                                                     const float* __restrict__ rowpart,
                                                     float* __restrict__ out) {
  extern __shared__ char smem[];  // 98304 core + 512 rowinv
  const int z = blockIdx.z;
  const int tileM = blockIdx.x * 128, tileN = blockIdx.y * 256;
  float* rinv = (float*)(smem + 98304);
  const int tid = threadIdx.x;
  if (tid < 128) {
    float s = 0.f;
#pragma unroll
    for (int t = 0; t < 8; ++t) s += rowpart[t * 8192 + z * 2048 + tileM + tid];
    rinv[tid] = 1.0f / s;
  }
  // core8's first barrier orders the rinv write before epilogue reads.
  f32x4 acc[16] = {};
  core8<1, 32>((const char*)P + (size_t)z * 8388608 + (size_t)tileM * 4096,
               (const char*)Vt + (size_t)z * 4194304 + (size_t)tileN * 4096, 4096, 4096,
               smem, acc);
  const int wave = tid >> 6, lane = tid & 63;
  const int wr = wave >> 2, wc = wave & 3, fr = lane & 15, fg = lane >> 4;
  float* O = out + (size_t)z * 2097152;
#pragma unroll
  for (int mi = 0; mi < 4; ++mi) {
#pragma unroll
    for (int jj = 0; jj < 4; ++jj) {
      const int r = wr * 64 + mi * 16 + fg * 4 + jj;
      const float inv = rinv[r];
#pragma unroll
      for (int n = 0; n < 4; ++n)
        O[(size_t)(tileM + r) * 1024 + tileN + wc * 64 + n * 16 + fr] =
            acc[mi * 4 + n][jj] * inv;
    }
  }
}

extern "C" void kernel_launch(void* const* d_in, const int* in_sizes, int n_in,
                              void* d_out, int out_size, void* d_ws, size_t ws_size,
                              hipStream_t stream) {
  if (ws_size < ((size_t)72 << 20)) return;
  const float* x = (const float*)d_in[0];
  const float* Wq = (const float*)d_in[1];
  const float* bq = (const float*)d_in[2];
  const float* Wk = (const float*)d_in[3];
  const float* bk = (const float*)d_in[4];
  const float* Wv = (const float*)d_in[5];
  const float* bv = (const float*)d_in[6];
  char* ws = (char*)d_ws;
  u16* xb = (u16*)(ws);                       // [0,16M); later P~ [4][2048][2048]
  u16* Pb = (u16*)(ws);
  u16* Qb = (u16*)(ws + ((size_t)16 << 20));
  u16* Kb = (u16*)(ws + ((size_t)32 << 20));
  u16* Vt = (u16*)(ws + ((size_t)48 << 20));
  u16* Wb = (u16*)(ws + ((size_t)64 << 20));
  float* rowpart = (float*)(ws + ((size_t)70 << 20));  // 256 KiB
  float* out = (float*)d_out;

  (void)hipFuncSetAttribute((const void*)proj8_kernel,
                            hipFuncAttributeMaxDynamicSharedMemorySize, 98304);
  (void)hipFuncSetAttribute((const void*)sc8_kernel,
                            hipFuncAttributeMaxDynamicSharedMemorySize, 131072);
  (void)hipFuncSetAttribute((const void*)pv8_kernel,
                            hipFuncAttributeMaxDynamicSharedMemorySize, 98816);

  cast_all_kernel<<<11264, 256, 0, stream>>>(x, Wq, Wk, Wv, xb, Wb);

  proj8_kernel<<<dim3(64, 12), 512, 98304, stream>>>(xb, Wb, bq, bk, bv, Qb, Vt);

  sc8_kernel<<<dim3(8, 8, 4), 512, 131072, stream>>>(Qb, Kb, Pb, rowpart);
  pv8_kernel<<<dim3(16, 4, 4), 512, 98816, stream>>>(Pb, Vt, rowpart, out);
}